// Round 13
// baseline (384.752 us; speedup 1.0000x reference)
//
#include <hip/hip_runtime.h>
#include <hip/hip_bf16.h>
#include <stdint.h>

// ---------------------------------------------------------------------------
// HandNet R15 (resubmit; previous round died to a container infra failure,
// same signature as Rounds 1/9 which both passed on unchanged resubmission).
// R14 + trans_gemm "B-direct" restructure.
// B (1152x1088 fp16 = 2.4MB) is permanently L2-hot (read by all blocks) and
// its MFMA fragment is a plain 16B/lane load (row bn+wc*64+ni*16+l16, cols
// k0+quad*8). So B now loads straight global->VGPR with a named 2-set
// register double-buffer (b0/b1), and ONLY A stays in the 3-buffer LDS ring.
// Halves barrier-coupled staging (16->8KB/K-step), halves LDS traffic,
// LDS 48->24KB (higher residency). Counted wait becomes vmcnt(6):
// steady-state outstanding = A(s+1)x2 + B(s)x4 = 6 (free); prologue (8 ops)
// drains exactly A(0). Issue order pinned with sched_barrier(0); compiler's
// B-use wait (B(s) issued after A(s+1)) transitively guarantees A landing
// before each barrier (same safety argument as validated R8, less coupling).
// enc/dec/prep identical to R14 (validated 344.3us).
// ---------------------------------------------------------------------------

#define ZSIZE 18874368   // 16384*1152  (z output)
#define AHALF 147456     // 8192*18     (ang half)
#define PHALF 442368     // AHALF*3     (pos half)

// ws layout (bytes)
#define WS_AE 0                  // 16384x1088 fp16 = 35651584
#define WS_WT 35651584           // 1152x1088 fp16  = 2506752
#define WS_PACK 38158336         // packed layer weights, 33280 fp16

// pack offsets (fp16 units) and padded row strides
#define P_E1 0        // enc1: 32 x 40
#define P_E2 1280     // enc2: 64 x 72
#define P_E3 5888     // enc3: 128 x 104
#define P_D1 19200    // dec1: 64 x 168
#define P_D2 29952    // dec2: 32 x 104  (contiguous after D1)

using f32x4 = __attribute__((ext_vector_type(4))) float;
using f16x8 = __attribute__((ext_vector_type(8))) _Float16;
using f16x4 = __attribute__((ext_vector_type(4))) _Float16;

__device__ __forceinline__ float tanh_fast(float x) {
    x = fminf(40.f, fmaxf(-40.f, x));
    float e = __expf(2.f * x);
    return (e - 1.f) * __builtin_amdgcn_rcpf(e + 1.f);
}
__device__ __forceinline__ float lrelu(float x) { return x > 0.f ? x : 0.01f * x; }

__device__ __forceinline__ void gload_lds16(const void* g, void* l) {
    __builtin_amdgcn_global_load_lds(
        (__attribute__((address_space(1))) unsigned int*)g,
        (__attribute__((address_space(3))) unsigned int*)l, 16, 0, 0);
}

// ---------------------------------------------------------------------------
// prep_all: merged pack_weights (blocks 0..259) + Wt transpose (260..1483).
// ---------------------------------------------------------------------------
__global__ __launch_bounds__(256) void prep_all(
    _Float16* __restrict__ P,
    const float* __restrict__ W, _Float16* __restrict__ Wt,
    const float* __restrict__ e1l, const float* __restrict__ e1u,
    const float* __restrict__ e2l, const float* __restrict__ e2u,
    const float* __restrict__ e3l, const float* __restrict__ e3u,
    const float* __restrict__ d1l, const float* __restrict__ d1u,
    const float* __restrict__ d2l, const float* __restrict__ d2u)
{
    __shared__ float t[32][33];
    const int b = blockIdx.x;
    const int tid = threadIdx.x;

    if (b < 260) {
        const int p = b / 52;
        const int e = (b - p * 52) * 256 + tid;
        int Np, Kp, KpP, N, din, ed, K0, off; const float *Wl, *Wu;
        switch (p) {
          case 0:  Np=32;  Kp=32;  KpP=40;  N=16; din=3;  ed=3; K0=8;  off=P_E1; Wl=e1l; Wu=e1u; break;
          case 1:  Np=64;  Kp=64;  KpP=72;  N=32; din=16; ed=3; K0=24; off=P_E2; Wl=e2l; Wu=e2u; break;
          case 2:  Np=128; Kp=96;  KpP=104; N=64; din=32; ed=3; K0=40; off=P_E3; Wl=e3l; Wu=e3u; break;
          case 3:  Np=64;  Kp=160; KpP=168; N=32; din=66; ed=6; K0=72; off=P_D1; Wl=d1l; Wu=d1u; break;
          default: Np=32;  Kp=96;  KpP=104; N=16; din=32; ed=6; K0=40; off=P_D2; Wl=d2l; Wu=d2u; break;
        }
        if (e >= Np * KpP) return;
        const int n = e / KpP, k = e - n * KpP;
        float v = 0.f;
        if (k < Kp) {
            if (n < N) {
                if (k < din)                          v = Wl[k * N + n];
                else if (k >= K0 && k < K0 + din)     v = Wl[(din + k - K0) * N + n];
                else if (k >= 2*K0 && k < 2*K0 + ed)  v = Wl[(2*din + k - 2*K0) * N + n];
            } else {
                if (k < din) v = Wu[k * N + (n - N)];
            }
        }
        P[off + e] = (_Float16)v;
    } else {
        const int pb = b - 260;
        const int bx = pb % 34, by = pb / 34;
        const int k0 = bx * 32, n0 = by * 32;
        const int tx = tid & 31, ty = tid >> 5;
        for (int i = ty; i < 32; i += 8)
            t[i][tx] = W[(size_t)(k0 + i) * 1152 + n0 + tx];
        __syncthreads();
        for (int i = ty; i < 32; i += 8)
            Wt[(size_t)(n0 + i) * 1088 + k0 + tx] = (_Float16)t[tx][i];
    }
}

// ---------------------------------------------------------------------------
// Fused encoder on MFMA: 8 graphs/block, nodes padded to 20 -> M=160 (10 Mt).
// Activation strides (fp16): x 8, ea 16, h1 24, h2 40 (all zero-padded).
// LDS map (fp16 units): SX 0(1280) | EA 1280(2560) | H1 3840(3840) |
//                       H2 7680(6400) | WQ 14080(13312) -> pool 27392.
// E1+E2 staged together at start; enc2 reads WQ+1280; E3 restaged after enc2.
// M-tiles per wave: {wave, wave+4, wave+8<10} (dec-proven pattern).
// ---------------------------------------------------------------------------
#define E_SX 0
#define E_EA 1280
#define E_H1 3840
#define E_H2 7680
#define E_WQ 14080

__global__ __launch_bounds__(256) void enc_kernel(
    const float* __restrict__ lx,  const float* __restrict__ rx,
    const float* __restrict__ lea, const float* __restrict__ rea,
    const float* __restrict__ b1l, const float* __restrict__ b1u,
    const float* __restrict__ b2l, const float* __restrict__ b2u,
    const float* __restrict__ b3l, const float* __restrict__ b3u,
    const _Float16* __restrict__ pack,
    _Float16* __restrict__ Ae)
{
    __shared__ __align__(16) _Float16 sm[27392];
    __shared__ float sb[224];

    const int tid = threadIdx.x;
    const int wave = tid >> 6, lane = tid & 63;
    const int quad = lane >> 4, l16 = lane & 15;
    const int g2b = blockIdx.x * 8;

    // zero activation pool (14080 fp16 = 7040 u32)
    for (int i = tid; i < 7040; i += 256) ((uint32_t*)sm)[i] = 0u;
    // E1+E2 weights (5888 fp16 = 736 uint4, contiguous in pack)
    { uint4* d = (uint4*)&sm[E_WQ]; const uint4* s = (const uint4*)(pack + P_E1);
      for (int i = tid; i < 736; i += 256) d[i] = s[i]; }
    for (int i = tid; i < 16; i += 256) { sb[i] = b1l[i]; sb[16 + i] = b1u[i]; }
    for (int i = tid; i < 32; i += 256) { sb[32 + i] = b2l[i]; sb[64 + i] = b2u[i]; }
    for (int i = tid; i < 64; i += 256) { sb[96 + i] = b3l[i]; sb[160 + i] = b3u[i]; }
    __syncthreads();

    // stage x, ea (8 graphs, all on same hand since g2b % 8 == 0)
    const float* xs = (g2b < 8192) ? lx  + (size_t)g2b * 51 : rx  + (size_t)(g2b - 8192) * 51;
    const float* es = (g2b < 8192) ? lea + (size_t)g2b * 48 : rea + (size_t)(g2b - 8192) * 48;
    for (int i = tid; i < 408; i += 256) {
        int g = i / 51, j = i - g * 51, node = j / 3, c = j - node * 3;
        sm[E_SX + (g * 20 + node) * 8 + c] = (_Float16)xs[i];
    }
    for (int i = tid; i < 384; i += 256) {
        int g = i / 48, j = i - g * 48, node = j / 3, c = j - node * 3;
        sm[E_EA + (g * 20 + node) * 16 + c] = (_Float16)es[i];
    }
    __syncthreads();

    // M-tiles owned: {wave, wave+4, wave+8<10}
    int mts[3] = { wave, wave + 4, wave + 8 };
    const bool has[3] = { true, true, wave < 2 };
    int gN[3], ndN[3], npN[3];
    #pragma unroll
    for (int t = 0; t < 3; t++) {
        const int r16 = mts[t] * 16 + l16;
        gN[t] = r16 / 20; ndN[t] = r16 - gN[t] * 20;
        npN[t] = ndN[t] ? ndN[t] - 1 : 0;
    }

    // ---- enc1: K'=32 (1 Kt), N'=32 (2 Nt) ----
    {
        f32x4 acc[3][2];
        #pragma unroll
        for (int t = 0; t < 3; t++)
            #pragma unroll
            for (int n = 0; n < 2; n++)
                #pragma unroll
                for (int r = 0; r < 4; r++) acc[t][n][r] = 0.f;
        f16x8 bfr[2];
        #pragma unroll
        for (int nt = 0; nt < 2; nt++)
            bfr[nt] = *(const f16x8*)&sm[E_WQ + (nt * 16 + l16) * 40 + quad * 8];
        #pragma unroll
        for (int t = 0; t < 3; t++) if (has[t]) {
            const int aD = E_SX + (gN[t] * 20 + ndN[t]) * 8;
            const int aS = E_SX + (gN[t] * 20 + npN[t]) * 8;
            const int aE = E_EA + (gN[t] * 20 + npN[t]) * 16;
            const int ch = quad;
            const int off = ch < 1 ? aD : (ch < 2 ? aS : aE + (ch - 2) * 8);
            f16x8 af = *(const f16x8*)&sm[off];
            #pragma unroll
            for (int nt = 0; nt < 2; nt++)
                acc[t][nt] = __builtin_amdgcn_mfma_f32_16x16x32_f16(af, bfr[nt], acc[t][nt], 0, 0, 0);
        }
        const int f = l16;
        #pragma unroll
        for (int t = 0; t < 3; t++) if (has[t]) {
            #pragma unroll
            for (int r = 0; r < 4; r++) {
                const int row = mts[t] * 16 + quad * 4 + r;
                const int g = row / 20, nd = row - g * 20;
                if (nd < 17) {
                    const float msg = acc[t][0][r] + sb[f];
                    const float u   = acc[t][1][r] + sb[16 + f];
                    sm[E_H1 + (g * 20 + nd) * 24 + f] =
                        (_Float16)(u + (nd ? lrelu(msg) : 0.f));
                }
            }
        }
    }
    __syncthreads();

    // ---- enc2: K'=64 (2 Kt), N'=64 (4 Nt), weights at WQ+1280 ----
    {
        f32x4 acc[3][4];
        #pragma unroll
        for (int t = 0; t < 3; t++)
            #pragma unroll
            for (int n = 0; n < 4; n++)
                #pragma unroll
                for (int r = 0; r < 4; r++) acc[t][n][r] = 0.f;
        #pragma unroll
        for (int Kt = 0; Kt < 2; Kt++) {
            f16x8 bfr[4];
            #pragma unroll
            for (int nt = 0; nt < 4; nt++)
                bfr[nt] = *(const f16x8*)&sm[E_WQ + 1280 + (nt * 16 + l16) * 72 + Kt * 32 + quad * 8];
            #pragma unroll
            for (int t = 0; t < 3; t++) if (has[t]) {
                const int aD = E_H1 + (gN[t] * 20 + ndN[t]) * 24;
                const int aS = E_H1 + (gN[t] * 20 + npN[t]) * 24;
                const int aE = E_EA + (gN[t] * 20 + npN[t]) * 16;
                const int ch = Kt * 4 + quad;
                const int off = ch < 3 ? aD + ch * 8
                              : (ch < 6 ? aS + (ch - 3) * 8 : aE + (ch - 6) * 8);
                f16x8 af = *(const f16x8*)&sm[off];
                #pragma unroll
                for (int nt = 0; nt < 4; nt++)
                    acc[t][nt] = __builtin_amdgcn_mfma_f32_16x16x32_f16(af, bfr[nt], acc[t][nt], 0, 0, 0);
            }
        }
        #pragma unroll
        for (int ntm = 0; ntm < 2; ntm++) {
            const int f = ntm * 16 + l16;
            #pragma unroll
            for (int t = 0; t < 3; t++) if (has[t]) {
                #pragma unroll
                for (int r = 0; r < 4; r++) {
                    const int row = mts[t] * 16 + quad * 4 + r;
                    const int g = row / 20, nd = row - g * 20;
                    if (nd < 17) {
                        const float msg = acc[t][ntm][r]     + sb[32 + f];
                        const float u   = acc[t][ntm + 2][r] + sb[64 + f];
                        sm[E_H2 + (g * 20 + nd) * 40 + f] =
                            (_Float16)(u + (nd ? lrelu(msg) : 0.f));
                    }
                }
            }
        }
    }
    __syncthreads();
    { uint4* d = (uint4*)&sm[E_WQ]; const uint4* s = (const uint4*)(pack + P_E3);
      for (int i = tid; i < 1664; i += 256) d[i] = s[i]; }  // 13312 fp16 = 1664 uint4
    __syncthreads();

    // ---- enc3: K'=96 (3 Kt), N'=128 (8 Nt) -> global Ae ----
    {
        f32x4 acc[3][8];
        #pragma unroll
        for (int t = 0; t < 3; t++)
            #pragma unroll
            for (int n = 0; n < 8; n++)
                #pragma unroll
                for (int r = 0; r < 4; r++) acc[t][n][r] = 0.f;
        #pragma unroll
        for (int Kt = 0; Kt < 3; Kt++) {
            f16x8 bfr[8];
            #pragma unroll
            for (int nt = 0; nt < 8; nt++)
                bfr[nt] = *(const f16x8*)&sm[E_WQ + (nt * 16 + l16) * 104 + Kt * 32 + quad * 8];
            #pragma unroll
            for (int t = 0; t < 3; t++) if (has[t]) {
                const int aD = E_H2 + (gN[t] * 20 + ndN[t]) * 40;
                const int aS = E_H2 + (gN[t] * 20 + npN[t]) * 40;
                const int aE = E_EA + (gN[t] * 20 + npN[t]) * 16;
                const int ch = Kt * 4 + quad;
                const int off = ch < 5 ? aD + ch * 8
                              : (ch < 10 ? aS + (ch - 5) * 8 : aE + (ch - 10) * 8);
                f16x8 af = *(const f16x8*)&sm[off];
                #pragma unroll
                for (int nt = 0; nt < 8; nt++)
                    acc[t][nt] = __builtin_amdgcn_mfma_f32_16x16x32_f16(af, bfr[nt], acc[t][nt], 0, 0, 0);
            }
        }
        #pragma unroll
        for (int ntm = 0; ntm < 4; ntm++) {
            const int f = ntm * 16 + l16;
            #pragma unroll
            for (int t = 0; t < 3; t++) if (has[t]) {
                #pragma unroll
                for (int r = 0; r < 4; r++) {
                    const int row = mts[t] * 16 + quad * 4 + r;
                    const int g = row / 20, nd = row - g * 20;
                    if (nd < 17) {
                        const float msg = acc[t][ntm][r]     + sb[96 + f];
                        const float u   = acc[t][ntm + 4][r] + sb[160 + f];
                        Ae[(size_t)(g2b + g) * 1088 + nd * 64 + f] =
                            (_Float16)(u + (nd ? lrelu(msg) : 0.f));
                    }
                }
            }
        }
    }
}

// ---------------------------------------------------------------------------
// trans GEMM fp16, "B-direct": 128x128 C-tile, K-step 32.
// A: 3-buffer LDS ring (24KB), 2 gload_lds per wave per K-step, XOR swizzle.
// B: fragments loaded straight global->VGPR (L2-hot, 2.4MB total), named
// 2-set register double-buffer b0/b1 (static indexing, no scratch).
// Counted wait vmcnt(6) before each raw barrier: steady-state outstanding =
// A(s+1)x2 + B(s)x4 = 6 (wait is free); prologue drains exactly A(0).
// Issue order pinned with sched_barrier(0). XCD swizzle + fast tanh kept.
// ---------------------------------------------------------------------------
__global__ __launch_bounds__(256) void trans_gemm(
    const _Float16* __restrict__ A, const _Float16* __restrict__ Bt,
    const float* __restrict__ bias, float* __restrict__ Z)
{
    __shared__ __align__(16) _Float16 As[3][128 * 32];
    const int tid = threadIdx.x;

    // XCD-chunk swizzle: 1152 blocks, 8 XCDs, 144 blocks/XCD chunk.
    const int id = blockIdx.x;
    const int swz = (id & 7) * 144 + (id >> 3);
    const int bm = (swz / 9) * 128, bn = (swz % 9) * 128;

    const int lane = tid & 63, wave = tid >> 6;
    const int wr = wave >> 1, wc = wave & 1;
    const int quad = lane >> 4, l16 = lane & 15;

    // A staging (R8-proven): 2 gload_lds per wave per K-step, XOR chunk swizzle
    const int row0 = wave * 32 + (lane >> 2);
    const int row1 = row0 + 16;
    const int q0 = (lane & 3) ^ ((row0 >> 1) & 3);
    const int q1 = (lane & 3) ^ ((row1 >> 1) & 3);
    const size_t gA0 = (size_t)(bm + row0) * 1088 + q0 * 8;
    const size_t gA1 = (size_t)(bm + row1) * 1088 + q1 * 8;
    const int ldsA0 = (wave * 32) * 32;
    const int ldsA1 = (wave * 32 + 16) * 32;

    int offA[4];
    size_t gB[4];
    #pragma unroll
    for (int i = 0; i < 4; i++) {
        const int ma = wr * 64 + i * 16 + l16;
        offA[i] = ma * 32 + (quad ^ ((ma >> 1) & 3)) * 8;
        const int nb = wc * 64 + i * 16 + l16;
        gB[i] = (size_t)(bn + nb) * 1088 + quad * 8;   // direct fragment addr
    }

    f32x4 acc[4][4];
    #pragma unroll
    for (int i = 0; i < 4; i++)
        #pragma unroll
        for (int j = 0; j < 4; j++)
            #pragma unroll
            for (int r = 0; r < 4; r++) acc[i][j][r] = 0.f;

    // prologue: A(0)->buf0, A(1)->buf1 (4 ops) THEN B(0) (4 ops); order pinned
    gload_lds16(A + gA0,      &As[0][ldsA0]);
    gload_lds16(A + gA1,      &As[0][ldsA1]);
    gload_lds16(A + gA0 + 32, &As[1][ldsA0]);
    gload_lds16(A + gA1 + 32, &As[1][ldsA1]);
    __builtin_amdgcn_sched_barrier(0);
    f16x8 b0[4], b1[4];
    #pragma unroll
    for (int ni = 0; ni < 4; ni++) b0[ni] = *(const f16x8*)&Bt[gB[ni]];
    __builtin_amdgcn_sched_barrier(0);

    int cb = 0;   // consume buffer (s % 3)
    int sb = 2;   // stage buffer ((s+2) % 3)
    for (int it = 0; it < 17; ++it) {
        const int s0 = 2 * it, s1 = s0 + 1;
        // ---- K-step s0: consume b0, prefetch b1 = B(s1) ----
        asm volatile("s_waitcnt vmcnt(6)" ::: "memory");
        __builtin_amdgcn_s_barrier();
        if (s0 + 2 < 34) {
            const int kn = (s0 + 2) * 32;
            gload_lds16(A + gA0 + kn, &As[sb][ldsA0]);
            gload_lds16(A + gA1 + kn, &As[sb][ldsA1]);
        }
        __builtin_amdgcn_sched_barrier(0);
        {
            const int kb = s1 * 32;
            #pragma unroll
            for (int ni = 0; ni < 4; ni++) b1[ni] = *(const f16x8*)&Bt[gB[ni] + kb];
        }
        __builtin_amdgcn_sched_barrier(0);
        {
            f16x8 af[4];
            #pragma unroll
            for (int mi = 0; mi < 4; mi++) af[mi] = *(const f16x8*)&As[cb][offA[mi]];
            #pragma unroll
            for (int mi = 0; mi < 4; mi++)
                #pragma unroll
                for (int ni = 0; ni < 4; ni++)
                    acc[mi][ni] = __builtin_amdgcn_mfma_f32_16x16x32_f16(
                        af[mi], b0[ni], acc[mi][ni], 0, 0, 0);
        }
        cb = (cb == 2) ? 0 : cb + 1;
        sb = (sb == 2) ? 0 : sb + 1;

        // ---- K-step s1: consume b1, prefetch b0 = B(s1+1) ----
        asm volatile("s_waitcnt vmcnt(6)" ::: "memory");
        __builtin_amdgcn_s_barrier();
        if (s1 + 2 < 34) {
            const int kn = (s1 + 2) * 32;
            gload_lds16(A + gA0 + kn, &As[sb][ldsA0]);
            gload_lds16(A + gA1 + kn, &As[sb][ldsA1]);
        }
        __builtin_amdgcn_sched_barrier(0);
        if (s1 + 1 < 34) {
            const int kb = (s1 + 1) * 32;
            #pragma unroll
            for (int ni = 0; ni < 4; ni++) b0[ni] = *(const f16x8*)&Bt[gB[ni] + kb];
        }
        __builtin_amdgcn_sched_barrier(0);
        {
            f16x8 af[4];
            #pragma unroll
            for (int mi = 0; mi < 4; mi++) af[mi] = *(const f16x8*)&As[cb][offA[mi]];
            #pragma unroll
            for (int mi = 0; mi < 4; mi++)
                #pragma unroll
                for (int ni = 0; ni < 4; ni++)
                    acc[mi][ni] = __builtin_amdgcn_mfma_f32_16x16x32_f16(
                        af[mi], b1[ni], acc[mi][ni], 0, 0, 0);
        }
        cb = (cb == 2) ? 0 : cb + 1;
        sb = (sb == 2) ? 0 : sb + 1;
    }

    #pragma unroll
    for (int mi = 0; mi < 4; mi++) {
        #pragma unroll
        for (int ni = 0; ni < 4; ni++) {
            const int n = bn + wc * 64 + ni * 16 + l16;
            const float bv = bias[n];
            #pragma unroll
            for (int r = 0; r < 4; r++) {
                const int m = bm + wr * 64 + mi * 16 + quad * 4 + r;
                Z[(size_t)m * 1152 + n] = tanh_fast(acc[mi][ni][r] + bv);
            }
        }
    }
}

// ---------------------------------------------------------------------------
// Fused decoder + FK on MFMA: 8 graphs/block, M=160 (10 Mt).
// Strides (fp16): xd 72, ea 16, h1 40, h2 16.
// LDS map (fp16): XD 0(11520) | EA 11520(2560) | H1 14080(6400) |
//                 H2 20480(2560) | WQ 23040(14080: D1+D2) -> pool 37120.
// D1+D2 staged once at start (contiguous in Pack); dec2 reads WQ+10752.
// FK/angle data staged in f32 LDS: ax 432, off 432, lo 144, up 144.
// ---------------------------------------------------------------------------
#define D_XD 0
#define D_EA 11520
#define D_H1 14080
#define D_H2 20480
#define D_WQ 23040
#define SB_B1L 0
#define SB_B1U 32
#define SB_B2L 64
#define SB_B2U 80
#define SB_W3L 96
#define SB_W3U 134
#define SB_B3L 150
#define SB_B3U 151
#define SB_ANG 152   // 144 floats

__global__ __launch_bounds__(256) void dec_kernel(
    const float* __restrict__ Zc,  const float* __restrict__ tea,
    const float* __restrict__ lo_, const float* __restrict__ up_,
    const float* __restrict__ off_, const int* __restrict__ par_,
    const float* __restrict__ ax_,
    const float* __restrict__ b1l, const float* __restrict__ b1u,
    const float* __restrict__ b2l, const float* __restrict__ b2u,
    const float* __restrict__ w3l, const float* __restrict__ b3l,
    const float* __restrict__ w3u, const float* __restrict__ b3u,
    const _Float16* __restrict__ pack,
    float* __restrict__ out)
{
    __shared__ __align__(16) _Float16 sm[37120];
    __shared__ __align__(16) float sfl[296];
    __shared__ __align__(16) float s_ax[432];
    __shared__ __align__(16) float s_off[432];
    __shared__ __align__(16) float s_lo[144];
    __shared__ __align__(16) float s_up[144];

    const int tid = threadIdx.x;
    const int wave = tid >> 6, lane = tid & 63;
    const int quad = lane >> 4, l16 = lane & 15;
    const int g2b = blockIdx.x * 8;
    const int hb = g2b & 8191;     // 8 graphs per block, same hand (g2b % 8 == 0)

    // zero activations (23040 fp16 = 11520 u32)
    for (int i = tid; i < 11520; i += 256) ((uint32_t*)sm)[i] = 0u;
    // D1+D2 weights (14080 fp16 = 1760 uint4, contiguous in pack)
    { uint4* d = (uint4*)&sm[D_WQ]; const uint4* s = (const uint4*)(pack + P_D1);
      for (int i = tid; i < 1760; i += 256) d[i] = s[i]; }
    for (int i = tid; i < 32; i += 256) { sfl[SB_B1L + i] = b1l[i]; sfl[SB_B1U + i] = b1u[i]; }
    for (int i = tid; i < 16; i += 256) { sfl[SB_B2L + i] = b2l[i]; sfl[SB_B2U + i] = b2u[i];
                                          sfl[SB_W3U + i] = w3u[i]; }
    for (int i = tid; i < 38; i += 256) sfl[SB_W3L + i] = w3l[i];
    if (tid == 0) { sfl[SB_B3L] = b3l[0]; sfl[SB_B3U] = b3u[0]; }

    // FK / angle inputs, coalesced float4 (all bases 16B-aligned: hb % 8 == 0)
    {
        const f32x4* axv = (const f32x4*)(ax_  + (size_t)hb * 54);
        const f32x4* ofv = (const f32x4*)(off_ + (size_t)hb * 54);
        for (int i = tid; i < 108; i += 256) {
            ((f32x4*)s_ax)[i]  = axv[i];
            ((f32x4*)s_off)[i] = ofv[i];
        }
        const f32x4* lov = (const f32x4*)(lo_ + (size_t)hb * 18);
        const f32x4* upv = (const f32x4*)(up_ + (size_t)hb * 18);
        for (int i = tid; i < 36; i += 256) {
            ((f32x4*)s_lo)[i] = lov[i];
            ((f32x4*)s_up)[i] = upv[i];
        }
    }
    __syncthreads();

    // stage xd = [z(64) | lo | up], ea -- vectorized
    {
        // z: 9216 f32 contiguous = 2304 float4, 9 per thread
        const f32x4* Zv = (const f32x4*)(Zc + (size_t)g2b * 1152);
        for (int i = tid; i < 2304; i += 256) {
            const f32x4 v = Zv[i];
            const int g = i / 288, rem = i - g * 288;
            const int node = rem >> 4, c = (rem & 15) << 2;
            f16x4 h;
            h[0] = (_Float16)v[0]; h[1] = (_Float16)v[1];
            h[2] = (_Float16)v[2]; h[3] = (_Float16)v[3];
            *(f16x4*)&sm[D_XD + (g * 20 + node) * 72 + c] = h;
        }
        // lo/up into xd cols 64,65 (from LDS f32 copies)
        for (int i = tid; i < 144; i += 256) {
            const int g = i / 18, node = i - g * 18;
            sm[D_XD + (g * 20 + node) * 72 + 64] = (_Float16)s_lo[i];
            sm[D_XD + (g * 20 + node) * 72 + 65] = (_Float16)s_up[i];
        }
        // ea: 816 f32 contiguous = 204 float4 (graph stride 102 not /4 -> per-elem scatter)
        const f32x4* Ev = (const f32x4*)(tea + (size_t)hb * 102);
        for (int i = tid; i < 204; i += 256) {
            const f32x4 v = Ev[i];
            #pragma unroll
            for (int e = 0; e < 4; e++) {
                const int f = 4 * i + e;
                const int g = f / 102, j = f - 102 * g;
                const int node = j / 6, c = j - node * 6;
                sm[D_EA + (g * 20 + node) * 16 + c] = (_Float16)v[e];
            }
        }
    }
    __syncthreads();

    // M-tiles owned: {wave, wave+4, wave+8<10}
    int mts[3] = { wave, wave + 4, wave + 8 };
    const bool has[3] = { true, true, wave < 2 };
    int gN[3], ndN[3], npN[3];
    #pragma unroll
    for (int t = 0; t < 3; t++) {
        const int r16 = mts[t] * 16 + l16;
        gN[t] = r16 / 20; ndN[t] = r16 - gN[t] * 20;
        npN[t] = ndN[t] ? ndN[t] - 1 : 0;
    }

    // ---- dec1: K'=160 (5 Kt), N'=64 (4 Nt) ----
    {
        f32x4 acc[3][4];
        #pragma unroll
        for (int t = 0; t < 3; t++)
            #pragma unroll
            for (int n = 0; n < 4; n++)
                #pragma unroll
                for (int r = 0; r < 4; r++) acc[t][n][r] = 0.f;
        #pragma unroll
        for (int Kt = 0; Kt < 5; Kt++) {
            f16x8 bfr[4];
            #pragma unroll
            for (int nt = 0; nt < 4; nt++)
                bfr[nt] = *(const f16x8*)&sm[D_WQ + (nt * 16 + l16) * 168 + Kt * 32 + quad * 8];
            #pragma unroll
            for (int t = 0; t < 3; t++) if (has[t]) {
                const int aD = D_XD + (gN[t] * 20 + ndN[t]) * 72;
                const int aS = D_XD + (gN[t] * 20 + npN[t]) * 72;
                const int aE = D_EA + (gN[t] * 20 + npN[t]) * 16;
                const int ch = Kt * 4 + quad;
                const int off = ch < 9 ? aD + ch * 8
                              : (ch < 18 ? aS + (ch - 9) * 8 : aE + (ch - 18) * 8);
                f16x8 af = *(const f16x8*)&sm[off];
                #pragma unroll
                for (int nt = 0; nt < 4; nt++)
                    acc[t][nt] = __builtin_amdgcn_mfma_f32_16x16x32_f16(af, bfr[nt], acc[t][nt], 0, 0, 0);
            }
        }
        #pragma unroll
        for (int ntm = 0; ntm < 2; ntm++) {
            const int f = ntm * 16 + l16;
            #pragma unroll
            for (int t = 0; t < 3; t++) if (has[t]) {
                #pragma unroll
                for (int r = 0; r < 4; r++) {
                    const int row = mts[t] * 16 + quad * 4 + r;
                    const int g = row / 20, nd = row - g * 20;
                    if (nd < 18) {
                        const float msg = acc[t][ntm][r]     + sfl[SB_B1L + f];
                        const float u   = acc[t][ntm + 2][r] + sfl[SB_B1U + f];
                        sm[D_H1 + (g * 20 + nd) * 40 + f] =
                            (_Float16)(u + (nd ? lrelu(msg) : 0.f));
                    }
                }
            }
        }
    }
    __syncthreads();

    // ---- dec2: K'=96 (3 Kt), N'=32 (2 Nt), weights at WQ+10752 ----
    {
        f32x4 acc[3][2];
        #pragma unroll
        for (int t = 0; t < 3; t++)
            #pragma unroll
            for (int n = 0; n < 2; n++)
                #pragma unroll
                for (int r = 0; r < 4; r++) acc[t][n][r] = 0.f;
        #pragma unroll
        for (int Kt = 0; Kt < 3; Kt++) {
            f16x8 bfr[2];
            #pragma unroll
            for (int nt = 0; nt < 2; nt++)
                bfr[nt] = *(const f16x8*)&sm[D_WQ + 10752 + (nt * 16 + l16) * 104 + Kt * 32 + quad * 8];
            #pragma unroll
            for (int t = 0; t < 3; t++) if (has[t]) {
                const int aD = D_H1 + (gN[t] * 20 + ndN[t]) * 40;
                const int aS = D_H1 + (gN[t] * 20 + npN[t]) * 40;
                const int aE = D_EA + (gN[t] * 20 + npN[t]) * 16;
                const int ch = Kt * 4 + quad;
                const int off = ch < 5 ? aD + ch * 8
                              : (ch < 10 ? aS + (ch - 5) * 8 : aE + (ch - 10) * 8);
                f16x8 af = *(const f16x8*)&sm[off];
                #pragma unroll
                for (int nt = 0; nt < 2; nt++)
                    acc[t][nt] = __builtin_amdgcn_mfma_f32_16x16x32_f16(af, bfr[nt], acc[t][nt], 0, 0, 0);
            }
        }
        const int f = l16;
        #pragma unroll
        for (int t = 0; t < 3; t++) if (has[t]) {
            #pragma unroll
            for (int r = 0; r < 4; r++) {
                const int row = mts[t] * 16 + quad * 4 + r;
                const int g = row / 20, nd = row - g * 20;
                if (nd < 18) {
                    const float msg = acc[t][0][r] + sfl[SB_B2L + f];
                    const float u   = acc[t][1][r] + sfl[SB_B2U + f];
                    sm[D_H2 + (g * 20 + nd) * 16 + f] =
                        (_Float16)(u + (nd ? lrelu(msg) : 0.f));
                }
            }
        }
    }
    __syncthreads();

    // ---- dec3 (N=1) + tanh + angle (VALU) ----
    if (tid < 144) {
        const int g = tid / 18, nd = tid - (tid / 18) * 18;
        const _Float16* hn = &sm[D_H2 + (g * 20 + nd) * 16];
        float acc = sfl[SB_B3U];
        #pragma unroll
        for (int c = 0; c < 16; c++) acc += (float)hn[c] * sfl[SB_W3U + c];
        if (nd > 0) {
            const _Float16* hp = &sm[D_H2 + (g * 20 + nd - 1) * 16];
            const _Float16* e  = &sm[D_EA + (g * 20 + nd - 1) * 16];
            float m = sfl[SB_B3L];
            #pragma unroll
            for (int c = 0; c < 16; c++) m += (float)hn[c] * sfl[SB_W3L + c];
            #pragma unroll
            for (int c = 0; c < 16; c++) m += (float)hp[c] * sfl[SB_W3L + 16 + c];
            #pragma unroll
            for (int c = 0; c < 6;  c++) m += (float)e[c]  * sfl[SB_W3L + 32 + c];
            acc += lrelu(m);
        }
        const float hd = tanh_fast(acc);
        const int g2 = g2b + g;
        const float lo = s_lo[tid], up = s_up[tid];
        const float ang = lo + (up - lo) * (hd + 1.f) * 0.5f;
        sfl[SB_ANG + tid] = ang;
        const size_t abase = (g2 < 8192) ? (size_t)ZSIZE + (size_t)g2 * 18
                                         : (size_t)ZSIZE + AHALF + PHALF + (size_t)(g2 - 8192) * 18;
        out[abase + nd] = ang;
    }
    __syncthreads();

    // ---- FK: sequential 18-joint chain, 3 threads per graph (one per row of
    // R). Row r of R_new = row r of R_prev times full local Rl; p_r needs only
    // row r of R_prev. All inputs from LDS (staged at kernel start); chain
    // topology (root j=0, parent j-1) as assumed by the message passing.
    if (tid < 24) {
        const int g = tid / 3, r = tid - (tid / 3) * 3;
        const int g2 = g2b + g;
        const size_t pbase = (g2 < 8192)
            ? (size_t)ZSIZE + AHALF + (size_t)g2 * 54
            : (size_t)ZSIZE + AHALF + PHALF + AHALF + (size_t)(g2 - 8192) * 54;
        float Rr0 = 0.f, Rr1 = 0.f, Rr2 = 0.f, pr = 0.f;
        #pragma unroll
        for (int j = 0; j < 18; j++) {
            const int m = g * 18 + j;
            const float a0 = s_ax[m * 3 + 0], a1 = s_ax[m * 3 + 1], a2 = s_ax[m * 3 + 2];
            const float o0 = s_off[m * 3 + 0], o1 = s_off[m * 3 + 1], o2 = s_off[m * 3 + 2];
            float s, c;
            __sincosf(sfl[SB_ANG + m], &s, &c);
            const float omc = 1.f - c;
            const float n2 = a0 * a0 + a1 * a1 + a2 * a2;
            const float dg = 1.f - omc * n2;
            const float L00 = dg + omc * a0 * a0;
            const float L01 = omc * a0 * a1 - s * a2;
            const float L02 = omc * a0 * a2 + s * a1;
            const float L10 = omc * a1 * a0 + s * a2;
            const float L11 = dg + omc * a1 * a1;
            const float L12 = omc * a1 * a2 - s * a0;
            const float L20 = omc * a2 * a0 - s * a1;
            const float L21 = omc * a2 * a1 + s * a0;
            const float L22 = dg + omc * a2 * a2;
            if (j == 0) {
                Rr0 = (r == 0) ? L00 : ((r == 1) ? L10 : L20);
                Rr1 = (r == 0) ? L01 : ((r == 1) ? L11 : L21);
                Rr2 = (r == 0) ? L02 : ((r == 1) ? L12 : L22);
                pr  = (r == 0) ? o0  : ((r == 1) ? o1  : o2);
            } else {
                pr += Rr0 * o0 + Rr1 * o1 + Rr2 * o2;
                const float t0 = Rr0 * L00 + Rr1 * L10 + Rr2 * L20;
                const float t1 = Rr0 * L01 + Rr1 * L11 + Rr2 * L21;
                const float t2 = Rr0 * L02 + Rr1 * L12 + Rr2 * L22;
                Rr0 = t0; Rr1 = t1; Rr2 = t2;
            }
            out[pbase + j * 3 + r] = pr;
        }
    }
}

// ---------------------------------------------------------------------------
extern "C" void kernel_launch(void* const* d_in, const int* in_sizes, int n_in,
                              void* d_out, int out_size, void* d_ws, size_t ws_size,
                              hipStream_t stream)
{
    int i_tw, i_tb, i_d1, i_d2, i_d3;
    if (n_in > 27 && in_sizes[26] == 1088 * 1152) {
        i_tw = 26; i_tb = 27; i_d1 = 28; i_d2 = 32; i_d3 = 36;
    } else {
        i_d1 = 26; i_d2 = 30; i_d3 = 34; i_tw = 38; i_tb = 39;
    }
    auto fp = [&](int i) { return (const float*)d_in[i]; };

    _Float16* Ae   = (_Float16*)((char*)d_ws + WS_AE);
    _Float16* Wt   = (_Float16*)((char*)d_ws + WS_WT);
    _Float16* Pack = (_Float16*)((char*)d_ws + WS_PACK);

    prep_all<<<1484, 256, 0, stream>>>(
        Pack, fp(i_tw), Wt,
        fp(14), fp(16), fp(18), fp(20), fp(22), fp(24),
        fp(i_d1), fp(i_d1 + 2), fp(i_d2), fp(i_d2 + 2));

    enc_kernel<<<2048, 256, 0, stream>>>(
        fp(0), fp(1), fp(4), fp(5),
        fp(15), fp(17), fp(19), fp(21), fp(23), fp(25),
        Pack, Ae);

    trans_gemm<<<1152, 256, 0, stream>>>(Ae, Wt, fp(i_tb), (float*)d_out);

    dec_kernel<<<2048, 256, 0, stream>>>(
        (const float*)d_out, fp(7), fp(8), fp(9), fp(10),
        (const int*)d_in[11], fp(12),
        fp(i_d1 + 1), fp(i_d1 + 3), fp(i_d2 + 1), fp(i_d2 + 3),
        fp(i_d3), fp(i_d3 + 1), fp(i_d3 + 2), fp(i_d3 + 3),
        Pack, (float*)d_out);
}

// Round 14
// 345.901 us; speedup vs baseline: 1.1123x; 1.1123x over previous
//
#include <hip/hip_runtime.h>
#include <hip/hip_bf16.h>
#include <stdint.h>

// ---------------------------------------------------------------------------
// HandNet R16: revert to the best-measured configuration (R14, 344.3us).
// R15's "B-direct" regressed trans 73.5 -> 116us: per-fragment B loads put
// lanes 0..15 at rows 2176B apart (16 scattered 16B segments/load, 4/K-step)
// -- the LDS staging WAS the coalescing layer for B. Reverted.
// trans: R8 3-buffer counted-vmcnt ring (A+B) + XCD swizzle + fast tanh.
// enc: 8 graphs/block dec-style geometry (R14). dec: latency-fixed (R6/R13).
// prep: merged pack+wt (R12).
// ---------------------------------------------------------------------------

#define ZSIZE 18874368   // 16384*1152  (z output)
#define AHALF 147456     // 8192*18     (ang half)
#define PHALF 442368     // AHALF*3     (pos half)

// ws layout (bytes)
#define WS_AE 0                  // 16384x1088 fp16 = 35651584
#define WS_WT 35651584           // 1152x1088 fp16  = 2506752
#define WS_PACK 38158336         // packed layer weights, 33280 fp16

// pack offsets (fp16 units) and padded row strides
#define P_E1 0        // enc1: 32 x 40
#define P_E2 1280     // enc2: 64 x 72
#define P_E3 5888     // enc3: 128 x 104
#define P_D1 19200    // dec1: 64 x 168
#define P_D2 29952    // dec2: 32 x 104  (contiguous after D1)

using f32x4 = __attribute__((ext_vector_type(4))) float;
using f16x8 = __attribute__((ext_vector_type(8))) _Float16;
using f16x4 = __attribute__((ext_vector_type(4))) _Float16;

__device__ __forceinline__ float tanh_fast(float x) {
    x = fminf(40.f, fmaxf(-40.f, x));
    float e = __expf(2.f * x);
    return (e - 1.f) * __builtin_amdgcn_rcpf(e + 1.f);
}
__device__ __forceinline__ float lrelu(float x) { return x > 0.f ? x : 0.01f * x; }

__device__ __forceinline__ void gload_lds16(const void* g, void* l) {
    __builtin_amdgcn_global_load_lds(
        (__attribute__((address_space(1))) unsigned int*)g,
        (__attribute__((address_space(3))) unsigned int*)l, 16, 0, 0);
}

// ---------------------------------------------------------------------------
// prep_all: merged pack_weights (blocks 0..259) + Wt transpose (260..1483).
// ---------------------------------------------------------------------------
__global__ __launch_bounds__(256) void prep_all(
    _Float16* __restrict__ P,
    const float* __restrict__ W, _Float16* __restrict__ Wt,
    const float* __restrict__ e1l, const float* __restrict__ e1u,
    const float* __restrict__ e2l, const float* __restrict__ e2u,
    const float* __restrict__ e3l, const float* __restrict__ e3u,
    const float* __restrict__ d1l, const float* __restrict__ d1u,
    const float* __restrict__ d2l, const float* __restrict__ d2u)
{
    __shared__ float t[32][33];
    const int b = blockIdx.x;
    const int tid = threadIdx.x;

    if (b < 260) {
        const int p = b / 52;
        const int e = (b - p * 52) * 256 + tid;
        int Np, Kp, KpP, N, din, ed, K0, off; const float *Wl, *Wu;
        switch (p) {
          case 0:  Np=32;  Kp=32;  KpP=40;  N=16; din=3;  ed=3; K0=8;  off=P_E1; Wl=e1l; Wu=e1u; break;
          case 1:  Np=64;  Kp=64;  KpP=72;  N=32; din=16; ed=3; K0=24; off=P_E2; Wl=e2l; Wu=e2u; break;
          case 2:  Np=128; Kp=96;  KpP=104; N=64; din=32; ed=3; K0=40; off=P_E3; Wl=e3l; Wu=e3u; break;
          case 3:  Np=64;  Kp=160; KpP=168; N=32; din=66; ed=6; K0=72; off=P_D1; Wl=d1l; Wu=d1u; break;
          default: Np=32;  Kp=96;  KpP=104; N=16; din=32; ed=6; K0=40; off=P_D2; Wl=d2l; Wu=d2u; break;
        }
        if (e >= Np * KpP) return;
        const int n = e / KpP, k = e - n * KpP;
        float v = 0.f;
        if (k < Kp) {
            if (n < N) {
                if (k < din)                          v = Wl[k * N + n];
                else if (k >= K0 && k < K0 + din)     v = Wl[(din + k - K0) * N + n];
                else if (k >= 2*K0 && k < 2*K0 + ed)  v = Wl[(2*din + k - 2*K0) * N + n];
            } else {
                if (k < din) v = Wu[k * N + (n - N)];
            }
        }
        P[off + e] = (_Float16)v;
    } else {
        const int pb = b - 260;
        const int bx = pb % 34, by = pb / 34;
        const int k0 = bx * 32, n0 = by * 32;
        const int tx = tid & 31, ty = tid >> 5;
        for (int i = ty; i < 32; i += 8)
            t[i][tx] = W[(size_t)(k0 + i) * 1152 + n0 + tx];
        __syncthreads();
        for (int i = ty; i < 32; i += 8)
            Wt[(size_t)(n0 + i) * 1088 + k0 + tx] = (_Float16)t[tx][i];
    }
}

// ---------------------------------------------------------------------------
// Fused encoder on MFMA: 8 graphs/block, nodes padded to 20 -> M=160 (10 Mt).
// Activation strides (fp16): x 8, ea 16, h1 24, h2 40 (all zero-padded).
// LDS map (fp16 units): SX 0(1280) | EA 1280(2560) | H1 3840(3840) |
//                       H2 7680(6400) | WQ 14080(13312) -> pool 27392.
// E1+E2 staged together at start; enc2 reads WQ+1280; E3 restaged after enc2.
// M-tiles per wave: {wave, wave+4, wave+8<10} (dec-proven pattern).
// ---------------------------------------------------------------------------
#define E_SX 0
#define E_EA 1280
#define E_H1 3840
#define E_H2 7680
#define E_WQ 14080

__global__ __launch_bounds__(256) void enc_kernel(
    const float* __restrict__ lx,  const float* __restrict__ rx,
    const float* __restrict__ lea, const float* __restrict__ rea,
    const float* __restrict__ b1l, const float* __restrict__ b1u,
    const float* __restrict__ b2l, const float* __restrict__ b2u,
    const float* __restrict__ b3l, const float* __restrict__ b3u,
    const _Float16* __restrict__ pack,
    _Float16* __restrict__ Ae)
{
    __shared__ __align__(16) _Float16 sm[27392];
    __shared__ float sb[224];

    const int tid = threadIdx.x;
    const int wave = tid >> 6, lane = tid & 63;
    const int quad = lane >> 4, l16 = lane & 15;
    const int g2b = blockIdx.x * 8;

    // zero activation pool (14080 fp16 = 7040 u32)
    for (int i = tid; i < 7040; i += 256) ((uint32_t*)sm)[i] = 0u;
    // E1+E2 weights (5888 fp16 = 736 uint4, contiguous in pack)
    { uint4* d = (uint4*)&sm[E_WQ]; const uint4* s = (const uint4*)(pack + P_E1);
      for (int i = tid; i < 736; i += 256) d[i] = s[i]; }
    for (int i = tid; i < 16; i += 256) { sb[i] = b1l[i]; sb[16 + i] = b1u[i]; }
    for (int i = tid; i < 32; i += 256) { sb[32 + i] = b2l[i]; sb[64 + i] = b2u[i]; }
    for (int i = tid; i < 64; i += 256) { sb[96 + i] = b3l[i]; sb[160 + i] = b3u[i]; }
    __syncthreads();

    // stage x, ea (8 graphs, all on same hand since g2b % 8 == 0)
    const float* xs = (g2b < 8192) ? lx  + (size_t)g2b * 51 : rx  + (size_t)(g2b - 8192) * 51;
    const float* es = (g2b < 8192) ? lea + (size_t)g2b * 48 : rea + (size_t)(g2b - 8192) * 48;
    for (int i = tid; i < 408; i += 256) {
        int g = i / 51, j = i - g * 51, node = j / 3, c = j - node * 3;
        sm[E_SX + (g * 20 + node) * 8 + c] = (_Float16)xs[i];
    }
    for (int i = tid; i < 384; i += 256) {
        int g = i / 48, j = i - g * 48, node = j / 3, c = j - node * 3;
        sm[E_EA + (g * 20 + node) * 16 + c] = (_Float16)es[i];
    }
    __syncthreads();

    // M-tiles owned: {wave, wave+4, wave+8<10}
    int mts[3] = { wave, wave + 4, wave + 8 };
    const bool has[3] = { true, true, wave < 2 };
    int gN[3], ndN[3], npN[3];
    #pragma unroll
    for (int t = 0; t < 3; t++) {
        const int r16 = mts[t] * 16 + l16;
        gN[t] = r16 / 20; ndN[t] = r16 - gN[t] * 20;
        npN[t] = ndN[t] ? ndN[t] - 1 : 0;
    }

    // ---- enc1: K'=32 (1 Kt), N'=32 (2 Nt) ----
    {
        f32x4 acc[3][2];
        #pragma unroll
        for (int t = 0; t < 3; t++)
            #pragma unroll
            for (int n = 0; n < 2; n++)
                #pragma unroll
                for (int r = 0; r < 4; r++) acc[t][n][r] = 0.f;
        f16x8 bfr[2];
        #pragma unroll
        for (int nt = 0; nt < 2; nt++)
            bfr[nt] = *(const f16x8*)&sm[E_WQ + (nt * 16 + l16) * 40 + quad * 8];
        #pragma unroll
        for (int t = 0; t < 3; t++) if (has[t]) {
            const int aD = E_SX + (gN[t] * 20 + ndN[t]) * 8;
            const int aS = E_SX + (gN[t] * 20 + npN[t]) * 8;
            const int aE = E_EA + (gN[t] * 20 + npN[t]) * 16;
            const int ch = quad;
            const int off = ch < 1 ? aD : (ch < 2 ? aS : aE + (ch - 2) * 8);
            f16x8 af = *(const f16x8*)&sm[off];
            #pragma unroll
            for (int nt = 0; nt < 2; nt++)
                acc[t][nt] = __builtin_amdgcn_mfma_f32_16x16x32_f16(af, bfr[nt], acc[t][nt], 0, 0, 0);
        }
        const int f = l16;
        #pragma unroll
        for (int t = 0; t < 3; t++) if (has[t]) {
            #pragma unroll
            for (int r = 0; r < 4; r++) {
                const int row = mts[t] * 16 + quad * 4 + r;
                const int g = row / 20, nd = row - g * 20;
                if (nd < 17) {
                    const float msg = acc[t][0][r] + sb[f];
                    const float u   = acc[t][1][r] + sb[16 + f];
                    sm[E_H1 + (g * 20 + nd) * 24 + f] =
                        (_Float16)(u + (nd ? lrelu(msg) : 0.f));
                }
            }
        }
    }
    __syncthreads();

    // ---- enc2: K'=64 (2 Kt), N'=64 (4 Nt), weights at WQ+1280 ----
    {
        f32x4 acc[3][4];
        #pragma unroll
        for (int t = 0; t < 3; t++)
            #pragma unroll
            for (int n = 0; n < 4; n++)
                #pragma unroll
                for (int r = 0; r < 4; r++) acc[t][n][r] = 0.f;
        #pragma unroll
        for (int Kt = 0; Kt < 2; Kt++) {
            f16x8 bfr[4];
            #pragma unroll
            for (int nt = 0; nt < 4; nt++)
                bfr[nt] = *(const f16x8*)&sm[E_WQ + 1280 + (nt * 16 + l16) * 72 + Kt * 32 + quad * 8];
            #pragma unroll
            for (int t = 0; t < 3; t++) if (has[t]) {
                const int aD = E_H1 + (gN[t] * 20 + ndN[t]) * 24;
                const int aS = E_H1 + (gN[t] * 20 + npN[t]) * 24;
                const int aE = E_EA + (gN[t] * 20 + npN[t]) * 16;
                const int ch = Kt * 4 + quad;
                const int off = ch < 3 ? aD + ch * 8
                              : (ch < 6 ? aS + (ch - 3) * 8 : aE + (ch - 6) * 8);
                f16x8 af = *(const f16x8*)&sm[off];
                #pragma unroll
                for (int nt = 0; nt < 4; nt++)
                    acc[t][nt] = __builtin_amdgcn_mfma_f32_16x16x32_f16(af, bfr[nt], acc[t][nt], 0, 0, 0);
            }
        }
        #pragma unroll
        for (int ntm = 0; ntm < 2; ntm++) {
            const int f = ntm * 16 + l16;
            #pragma unroll
            for (int t = 0; t < 3; t++) if (has[t]) {
                #pragma unroll
                for (int r = 0; r < 4; r++) {
                    const int row = mts[t] * 16 + quad * 4 + r;
                    const int g = row / 20, nd = row - g * 20;
                    if (nd < 17) {
                        const float msg = acc[t][ntm][r]     + sb[32 + f];
                        const float u   = acc[t][ntm + 2][r] + sb[64 + f];
                        sm[E_H2 + (g * 20 + nd) * 40 + f] =
                            (_Float16)(u + (nd ? lrelu(msg) : 0.f));
                    }
                }
            }
        }
    }
    __syncthreads();
    { uint4* d = (uint4*)&sm[E_WQ]; const uint4* s = (const uint4*)(pack + P_E3);
      for (int i = tid; i < 1664; i += 256) d[i] = s[i]; }  // 13312 fp16 = 1664 uint4
    __syncthreads();

    // ---- enc3: K'=96 (3 Kt), N'=128 (8 Nt) -> global Ae ----
    {
        f32x4 acc[3][8];
        #pragma unroll
        for (int t = 0; t < 3; t++)
            #pragma unroll
            for (int n = 0; n < 8; n++)
                #pragma unroll
                for (int r = 0; r < 4; r++) acc[t][n][r] = 0.f;
        #pragma unroll
        for (int Kt = 0; Kt < 3; Kt++) {
            f16x8 bfr[8];
            #pragma unroll
            for (int nt = 0; nt < 8; nt++)
                bfr[nt] = *(const f16x8*)&sm[E_WQ + (nt * 16 + l16) * 104 + Kt * 32 + quad * 8];
            #pragma unroll
            for (int t = 0; t < 3; t++) if (has[t]) {
                const int aD = E_H2 + (gN[t] * 20 + ndN[t]) * 40;
                const int aS = E_H2 + (gN[t] * 20 + npN[t]) * 40;
                const int aE = E_EA + (gN[t] * 20 + npN[t]) * 16;
                const int ch = Kt * 4 + quad;
                const int off = ch < 5 ? aD + ch * 8
                              : (ch < 10 ? aS + (ch - 5) * 8 : aE + (ch - 10) * 8);
                f16x8 af = *(const f16x8*)&sm[off];
                #pragma unroll
                for (int nt = 0; nt < 8; nt++)
                    acc[t][nt] = __builtin_amdgcn_mfma_f32_16x16x32_f16(af, bfr[nt], acc[t][nt], 0, 0, 0);
            }
        }
        #pragma unroll
        for (int ntm = 0; ntm < 4; ntm++) {
            const int f = ntm * 16 + l16;
            #pragma unroll
            for (int t = 0; t < 3; t++) if (has[t]) {
                #pragma unroll
                for (int r = 0; r < 4; r++) {
                    const int row = mts[t] * 16 + quad * 4 + r;
                    const int g = row / 20, nd = row - g * 20;
                    if (nd < 17) {
                        const float msg = acc[t][ntm][r]     + sb[96 + f];
                        const float u   = acc[t][ntm + 4][r] + sb[160 + f];
                        Ae[(size_t)(g2b + g) * 1088 + nd * 64 + f] =
                            (_Float16)(u + (nd ? lrelu(msg) : 0.f));
                    }
                }
            }
        }
    }
}

// ---------------------------------------------------------------------------
// trans GEMM fp16: 128x128 C-tile, K-step 32, 3-buffer LDS ring, 2 stages in
// flight across a raw s_barrier guarded by counted s_waitcnt vmcnt(4) (R8
// structure, best measured). 1D grid + bijective XCD-chunk swizzle (R11).
// Fast-tanh epilogue (R12).
// ---------------------------------------------------------------------------
__global__ __launch_bounds__(256) void trans_gemm(
    const _Float16* __restrict__ A, const _Float16* __restrict__ Bt,
    const float* __restrict__ bias, float* __restrict__ Z)
{
    __shared__ __align__(16) _Float16 As[3][128 * 32];
    __shared__ __align__(16) _Float16 Bs[3][128 * 32];
    const int tid = threadIdx.x;

    // XCD-chunk swizzle: 1152 blocks, 8 XCDs, 144 blocks/XCD chunk.
    const int id = blockIdx.x;
    const int swz = (id & 7) * 144 + (id >> 3);
    const int bm = (swz / 9) * 128, bn = (swz % 9) * 128;

    const int lane = tid & 63, wave = tid >> 6;
    const int wr = wave >> 1, wc = wave & 1;
    const int quad = lane >> 4, l16 = lane & 15;

    const int row0 = wave * 32 + (lane >> 2);
    const int row1 = row0 + 16;
    const int q0 = (lane & 3) ^ ((row0 >> 1) & 3);
    const int q1 = (lane & 3) ^ ((row1 >> 1) & 3);
    const size_t gA0 = (size_t)(bm + row0) * 1088 + q0 * 8;
    const size_t gA1 = (size_t)(bm + row1) * 1088 + q1 * 8;
    const size_t gB0 = (size_t)(bn + row0) * 1088 + q0 * 8;
    const size_t gB1 = (size_t)(bn + row1) * 1088 + q1 * 8;
    const int ldsA0 = (wave * 32) * 32;
    const int ldsA1 = (wave * 32 + 16) * 32;

    int offA[4], offB[4];
    #pragma unroll
    for (int i = 0; i < 4; i++) {
        const int ma = wr * 64 + i * 16 + l16;
        offA[i] = ma * 32 + (quad ^ ((ma >> 1) & 3)) * 8;
        const int nb = wc * 64 + i * 16 + l16;
        offB[i] = nb * 32 + (quad ^ ((nb >> 1) & 3)) * 8;
    }

    f32x4 acc[4][4];
    #pragma unroll
    for (int i = 0; i < 4; i++)
        #pragma unroll
        for (int j = 0; j < 4; j++)
            #pragma unroll
            for (int r = 0; r < 4; r++) acc[i][j][r] = 0.f;

    // prologue: stage tiles 0 and 1 into buffers 0 and 1 (8 loads in flight)
    gload_lds16(A + gA0,       &As[0][ldsA0]);
    gload_lds16(A + gA1,       &As[0][ldsA1]);
    gload_lds16(Bt + gB0,      &Bs[0][ldsA0]);
    gload_lds16(Bt + gB1,      &Bs[0][ldsA1]);
    gload_lds16(A + gA0 + 32,  &As[1][ldsA0]);
    gload_lds16(A + gA1 + 32,  &As[1][ldsA1]);
    gload_lds16(Bt + gB0 + 32, &Bs[1][ldsA0]);
    gload_lds16(Bt + gB1 + 32, &Bs[1][ldsA1]);

    int cb = 0;   // consume buffer index (t % 3)
    int sb = 2;   // stage buffer index ((t+2) % 3)
    for (int t = 0; t < 34; ++t) {
        // wait for own stage-t loads (oldest 4), keep t+1/t+2 in flight
        if (t < 33) asm volatile("s_waitcnt vmcnt(4)" ::: "memory");
        else        asm volatile("s_waitcnt vmcnt(0)" ::: "memory");
        __builtin_amdgcn_s_barrier();
        if (t + 2 < 34) {
            const int k0 = (t + 2) * 32;
            gload_lds16(A + gA0 + k0,  &As[sb][ldsA0]);
            gload_lds16(A + gA1 + k0,  &As[sb][ldsA1]);
            gload_lds16(Bt + gB0 + k0, &Bs[sb][ldsA0]);
            gload_lds16(Bt + gB1 + k0, &Bs[sb][ldsA1]);
        }
        f16x8 af[4], bfr[4];
        #pragma unroll
        for (int mi = 0; mi < 4; mi++) af[mi]  = *(const f16x8*)&As[cb][offA[mi]];
        #pragma unroll
        for (int ni = 0; ni < 4; ni++) bfr[ni] = *(const f16x8*)&Bs[cb][offB[ni]];
        #pragma unroll
        for (int mi = 0; mi < 4; mi++)
            #pragma unroll
            for (int ni = 0; ni < 4; ni++)
                acc[mi][ni] = __builtin_amdgcn_mfma_f32_16x16x32_f16(
                    af[mi], bfr[ni], acc[mi][ni], 0, 0, 0);
        cb = (cb == 2) ? 0 : cb + 1;
        sb = (sb == 2) ? 0 : sb + 1;
    }

    #pragma unroll
    for (int mi = 0; mi < 4; mi++) {
        #pragma unroll
        for (int ni = 0; ni < 4; ni++) {
            const int n = bn + wc * 64 + ni * 16 + l16;
            const float bv = bias[n];
            #pragma unroll
            for (int r = 0; r < 4; r++) {
                const int m = bm + wr * 64 + mi * 16 + quad * 4 + r;
                Z[(size_t)m * 1152 + n] = tanh_fast(acc[mi][ni][r] + bv);
            }
        }
    }
}

// ---------------------------------------------------------------------------
// Fused decoder + FK on MFMA: 8 graphs/block, M=160 (10 Mt).
// Strides (fp16): xd 72, ea 16, h1 40, h2 16.
// LDS map (fp16): XD 0(11520) | EA 11520(2560) | H1 14080(6400) |
//                 H2 20480(2560) | WQ 23040(14080: D1+D2) -> pool 37120.
// D1+D2 staged once at start (contiguous in Pack); dec2 reads WQ+10752.
// FK/angle data staged in f32 LDS: ax 432, off 432, lo 144, up 144.
// ---------------------------------------------------------------------------
#define D_XD 0
#define D_EA 11520
#define D_H1 14080
#define D_H2 20480
#define D_WQ 23040
#define SB_B1L 0
#define SB_B1U 32
#define SB_B2L 64
#define SB_B2U 80
#define SB_W3L 96
#define SB_W3U 134
#define SB_B3L 150
#define SB_B3U 151
#define SB_ANG 152   // 144 floats

__global__ __launch_bounds__(256) void dec_kernel(
    const float* __restrict__ Zc,  const float* __restrict__ tea,
    const float* __restrict__ lo_, const float* __restrict__ up_,
    const float* __restrict__ off_, const int* __restrict__ par_,
    const float* __restrict__ ax_,
    const float* __restrict__ b1l, const float* __restrict__ b1u,
    const float* __restrict__ b2l, const float* __restrict__ b2u,
    const float* __restrict__ w3l, const float* __restrict__ b3l,
    const float* __restrict__ w3u, const float* __restrict__ b3u,
    const _Float16* __restrict__ pack,
    float* __restrict__ out)
{
    __shared__ __align__(16) _Float16 sm[37120];
    __shared__ __align__(16) float sfl[296];
    __shared__ __align__(16) float s_ax[432];
    __shared__ __align__(16) float s_off[432];
    __shared__ __align__(16) float s_lo[144];
    __shared__ __align__(16) float s_up[144];

    const int tid = threadIdx.x;
    const int wave = tid >> 6, lane = tid & 63;
    const int quad = lane >> 4, l16 = lane & 15;
    const int g2b = blockIdx.x * 8;
    const int hb = g2b & 8191;     // 8 graphs per block, same hand (g2b % 8 == 0)

    // zero activations (23040 fp16 = 11520 u32)
    for (int i = tid; i < 11520; i += 256) ((uint32_t*)sm)[i] = 0u;
    // D1+D2 weights (14080 fp16 = 1760 uint4, contiguous in pack)
    { uint4* d = (uint4*)&sm[D_WQ]; const uint4* s = (const uint4*)(pack + P_D1);
      for (int i = tid; i < 1760; i += 256) d[i] = s[i]; }
    for (int i = tid; i < 32; i += 256) { sfl[SB_B1L + i] = b1l[i]; sfl[SB_B1U + i] = b1u[i]; }
    for (int i = tid; i < 16; i += 256) { sfl[SB_B2L + i] = b2l[i]; sfl[SB_B2U + i] = b2u[i];
                                          sfl[SB_W3U + i] = w3u[i]; }
    for (int i = tid; i < 38; i += 256) sfl[SB_W3L + i] = w3l[i];
    if (tid == 0) { sfl[SB_B3L] = b3l[0]; sfl[SB_B3U] = b3u[0]; }

    // FK / angle inputs, coalesced float4 (all bases 16B-aligned: hb % 8 == 0)
    {
        const f32x4* axv = (const f32x4*)(ax_  + (size_t)hb * 54);
        const f32x4* ofv = (const f32x4*)(off_ + (size_t)hb * 54);
        for (int i = tid; i < 108; i += 256) {
            ((f32x4*)s_ax)[i]  = axv[i];
            ((f32x4*)s_off)[i] = ofv[i];
        }
        const f32x4* lov = (const f32x4*)(lo_ + (size_t)hb * 18);
        const f32x4* upv = (const f32x4*)(up_ + (size_t)hb * 18);
        for (int i = tid; i < 36; i += 256) {
            ((f32x4*)s_lo)[i] = lov[i];
            ((f32x4*)s_up)[i] = upv[i];
        }
    }
    __syncthreads();

    // stage xd = [z(64) | lo | up], ea -- vectorized
    {
        // z: 9216 f32 contiguous = 2304 float4, 9 per thread
        const f32x4* Zv = (const f32x4*)(Zc + (size_t)g2b * 1152);
        for (int i = tid; i < 2304; i += 256) {
            const f32x4 v = Zv[i];
            const int g = i / 288, rem = i - g * 288;
            const int node = rem >> 4, c = (rem & 15) << 2;
            f16x4 h;
            h[0] = (_Float16)v[0]; h[1] = (_Float16)v[1];
            h[2] = (_Float16)v[2]; h[3] = (_Float16)v[3];
            *(f16x4*)&sm[D_XD + (g * 20 + node) * 72 + c] = h;
        }
        // lo/up into xd cols 64,65 (from LDS f32 copies)
        for (int i = tid; i < 144; i += 256) {
            const int g = i / 18, node = i - g * 18;
            sm[D_XD + (g * 20 + node) * 72 + 64] = (_Float16)s_lo[i];
            sm[D_XD + (g * 20 + node) * 72 + 65] = (_Float16)s_up[i];
        }
        // ea: 816 f32 contiguous = 204 float4 (graph stride 102 not /4 -> per-elem scatter)
        const f32x4* Ev = (const f32x4*)(tea + (size_t)hb * 102);
        for (int i = tid; i < 204; i += 256) {
            const f32x4 v = Ev[i];
            #pragma unroll
            for (int e = 0; e < 4; e++) {
                const int f = 4 * i + e;
                const int g = f / 102, j = f - 102 * g;
                const int node = j / 6, c = j - node * 6;
                sm[D_EA + (g * 20 + node) * 16 + c] = (_Float16)v[e];
            }
        }
    }
    __syncthreads();

    // M-tiles owned: {wave, wave+4, wave+8<10}
    int mts[3] = { wave, wave + 4, wave + 8 };
    const bool has[3] = { true, true, wave < 2 };
    int gN[3], ndN[3], npN[3];
    #pragma unroll
    for (int t = 0; t < 3; t++) {
        const int r16 = mts[t] * 16 + l16;
        gN[t] = r16 / 20; ndN[t] = r16 - gN[t] * 20;
        npN[t] = ndN[t] ? ndN[t] - 1 : 0;
    }

    // ---- dec1: K'=160 (5 Kt), N'=64 (4 Nt) ----
    {
        f32x4 acc[3][4];
        #pragma unroll
        for (int t = 0; t < 3; t++)
            #pragma unroll
            for (int n = 0; n < 4; n++)
                #pragma unroll
                for (int r = 0; r < 4; r++) acc[t][n][r] = 0.f;
        #pragma unroll
        for (int Kt = 0; Kt < 5; Kt++) {
            f16x8 bfr[4];
            #pragma unroll
            for (int nt = 0; nt < 4; nt++)
                bfr[nt] = *(const f16x8*)&sm[D_WQ + (nt * 16 + l16) * 168 + Kt * 32 + quad * 8];
            #pragma unroll
            for (int t = 0; t < 3; t++) if (has[t]) {
                const int aD = D_XD + (gN[t] * 20 + ndN[t]) * 72;
                const int aS = D_XD + (gN[t] * 20 + npN[t]) * 72;
                const int aE = D_EA + (gN[t] * 20 + npN[t]) * 16;
                const int ch = Kt * 4 + quad;
                const int off = ch < 9 ? aD + ch * 8
                              : (ch < 18 ? aS + (ch - 9) * 8 : aE + (ch - 18) * 8);
                f16x8 af = *(const f16x8*)&sm[off];
                #pragma unroll
                for (int nt = 0; nt < 4; nt++)
                    acc[t][nt] = __builtin_amdgcn_mfma_f32_16x16x32_f16(af, bfr[nt], acc[t][nt], 0, 0, 0);
            }
        }
        #pragma unroll
        for (int ntm = 0; ntm < 2; ntm++) {
            const int f = ntm * 16 + l16;
            #pragma unroll
            for (int t = 0; t < 3; t++) if (has[t]) {
                #pragma unroll
                for (int r = 0; r < 4; r++) {
                    const int row = mts[t] * 16 + quad * 4 + r;
                    const int g = row / 20, nd = row - g * 20;
                    if (nd < 18) {
                        const float msg = acc[t][ntm][r]     + sfl[SB_B1L + f];
                        const float u   = acc[t][ntm + 2][r] + sfl[SB_B1U + f];
                        sm[D_H1 + (g * 20 + nd) * 40 + f] =
                            (_Float16)(u + (nd ? lrelu(msg) : 0.f));
                    }
                }
            }
        }
    }
    __syncthreads();

    // ---- dec2: K'=96 (3 Kt), N'=32 (2 Nt), weights at WQ+10752 ----
    {
        f32x4 acc[3][2];
        #pragma unroll
        for (int t = 0; t < 3; t++)
            #pragma unroll
            for (int n = 0; n < 2; n++)
                #pragma unroll
                for (int r = 0; r < 4; r++) acc[t][n][r] = 0.f;
        #pragma unroll
        for (int Kt = 0; Kt < 3; Kt++) {
            f16x8 bfr[2];
            #pragma unroll
            for (int nt = 0; nt < 2; nt++)
                bfr[nt] = *(const f16x8*)&sm[D_WQ + 10752 + (nt * 16 + l16) * 104 + Kt * 32 + quad * 8];
            #pragma unroll
            for (int t = 0; t < 3; t++) if (has[t]) {
                const int aD = D_H1 + (gN[t] * 20 + ndN[t]) * 40;
                const int aS = D_H1 + (gN[t] * 20 + npN[t]) * 40;
                const int aE = D_EA + (gN[t] * 20 + npN[t]) * 16;
                const int ch = Kt * 4 + quad;
                const int off = ch < 5 ? aD + ch * 8
                              : (ch < 10 ? aS + (ch - 5) * 8 : aE + (ch - 10) * 8);
                f16x8 af = *(const f16x8*)&sm[off];
                #pragma unroll
                for (int nt = 0; nt < 2; nt++)
                    acc[t][nt] = __builtin_amdgcn_mfma_f32_16x16x32_f16(af, bfr[nt], acc[t][nt], 0, 0, 0);
            }
        }
        const int f = l16;
        #pragma unroll
        for (int t = 0; t < 3; t++) if (has[t]) {
            #pragma unroll
            for (int r = 0; r < 4; r++) {
                const int row = mts[t] * 16 + quad * 4 + r;
                const int g = row / 20, nd = row - g * 20;
                if (nd < 18) {
                    const float msg = acc[t][0][r] + sfl[SB_B2L + f];
                    const float u   = acc[t][1][r] + sfl[SB_B2U + f];
                    sm[D_H2 + (g * 20 + nd) * 16 + f] =
                        (_Float16)(u + (nd ? lrelu(msg) : 0.f));
                }
            }
        }
    }
    __syncthreads();

    // ---- dec3 (N=1) + tanh + angle (VALU) ----
    if (tid < 144) {
        const int g = tid / 18, nd = tid - (tid / 18) * 18;
        const _Float16* hn = &sm[D_H2 + (g * 20 + nd) * 16];
        float acc = sfl[SB_B3U];
        #pragma unroll
        for (int c = 0; c < 16; c++) acc += (float)hn[c] * sfl[SB_W3U + c];
        if (nd > 0) {
            const _Float16* hp = &sm[D_H2 + (g * 20 + nd - 1) * 16];
            const _Float16* e  = &sm[D_EA + (g * 20 + nd - 1) * 16];
            float m = sfl[SB_B3L];
            #pragma unroll
            for (int c = 0; c < 16; c++) m += (float)hn[c] * sfl[SB_W3L + c];
            #pragma unroll
            for (int c = 0; c < 16; c++) m += (float)hp[c] * sfl[SB_W3L + 16 + c];
            #pragma unroll
            for (int c = 0; c < 6;  c++) m += (float)e[c]  * sfl[SB_W3L + 32 + c];
            acc += lrelu(m);
        }
        const float hd = tanh_fast(acc);
        const int g2 = g2b + g;
        const float lo = s_lo[tid], up = s_up[tid];
        const float ang = lo + (up - lo) * (hd + 1.f) * 0.5f;
        sfl[SB_ANG + tid] = ang;
        const size_t abase = (g2 < 8192) ? (size_t)ZSIZE + (size_t)g2 * 18
                                         : (size_t)ZSIZE + AHALF + PHALF + (size_t)(g2 - 8192) * 18;
        out[abase + nd] = ang;
    }
    __syncthreads();

    // ---- FK: sequential 18-joint chain, 3 threads per graph (one per row of
    // R). Row r of R_new = row r of R_prev times full local Rl; p_r needs only
    // row r of R_prev. All inputs from LDS (staged at kernel start); chain
    // topology (root j=0, parent j-1) as assumed by the message passing.
    if (tid < 24) {
        const int g = tid / 3, r = tid - (tid / 3) * 3;
        const int g2 = g2b + g;
        const size_t pbase = (g2 < 8192)
            ? (size_t)ZSIZE + AHALF + (size_t)g2 * 54
            : (size_t)ZSIZE + AHALF + PHALF + AHALF + (size_t)(g2 - 8192) * 54;
        float Rr0 = 0.f, Rr1 = 0.f, Rr2 = 0.f, pr = 0.f;
        #pragma unroll
        for (int j = 0; j < 18; j++) {
            const int m = g * 18 + j;
            const float a0 = s_ax[m * 3 + 0], a1 = s_ax[m * 3 + 1], a2 = s_ax[m * 3 + 2];
            const float o0 = s_off[m * 3 + 0], o1 = s_off[m * 3 + 1], o2 = s_off[m * 3 + 2];
            float s, c;
            __sincosf(sfl[SB_ANG + m], &s, &c);
            const float omc = 1.f - c;
            const float n2 = a0 * a0 + a1 * a1 + a2 * a2;
            const float dg = 1.f - omc * n2;
            const float L00 = dg + omc * a0 * a0;
            const float L01 = omc * a0 * a1 - s * a2;
            const float L02 = omc * a0 * a2 + s * a1;
            const float L10 = omc * a1 * a0 + s * a2;
            const float L11 = dg + omc * a1 * a1;
            const float L12 = omc * a1 * a2 - s * a0;
            const float L20 = omc * a2 * a0 - s * a1;
            const float L21 = omc * a2 * a1 + s * a0;
            const float L22 = dg + omc * a2 * a2;
            if (j == 0) {
                Rr0 = (r == 0) ? L00 : ((r == 1) ? L10 : L20);
                Rr1 = (r == 0) ? L01 : ((r == 1) ? L11 : L21);
                Rr2 = (r == 0) ? L02 : ((r == 1) ? L12 : L22);
                pr  = (r == 0) ? o0  : ((r == 1) ? o1  : o2);
            } else {
                pr += Rr0 * o0 + Rr1 * o1 + Rr2 * o2;
                const float t0 = Rr0 * L00 + Rr1 * L10 + Rr2 * L20;
                const float t1 = Rr0 * L01 + Rr1 * L11 + Rr2 * L21;
                const float t2 = Rr0 * L02 + Rr1 * L12 + Rr2 * L22;
                Rr0 = t0; Rr1 = t1; Rr2 = t2;
            }
            out[pbase + j * 3 + r] = pr;
        }
    }
}

// ---------------------------------------------------------------------------
extern "C" void kernel_launch(void* const* d_in, const int* in_sizes, int n_in,
                              void* d_out, int out_size, void* d_ws, size_t ws_size,
                              hipStream_t stream)
{
    int i_tw, i_tb, i_d1, i_d2, i_d3;
    if (n_in > 27 && in_sizes[26] == 1088 * 1152) {
        i_tw = 26; i_tb = 27; i_d1 = 28; i_d2 = 32; i_d3 = 36;
    } else {
        i_d1 = 26; i_d2 = 30; i_d3 = 34; i_tw = 38; i_tb = 39;
    }
    auto fp = [&](int i) { return (const float*)d_in[i]; };

    _Float16* Ae   = (_Float16*)((char*)d_ws + WS_AE);
    _Float16* Wt   = (_Float16*)((char*)d_ws + WS_WT);
    _Float16* Pack = (_Float16*)((char*)d_ws + WS_PACK);

    prep_all<<<1484, 256, 0, stream>>>(
        Pack, fp(i_tw), Wt,
        fp(14), fp(16), fp(18), fp(20), fp(22), fp(24),
        fp(i_d1), fp(i_d1 + 2), fp(i_d2), fp(i_d2 + 2));

    enc_kernel<<<2048, 256, 0, stream>>>(
        fp(0), fp(1), fp(4), fp(5),
        fp(15), fp(17), fp(19), fp(21), fp(23), fp(25),
        Pack, Ae);

    trans_gemm<<<1152, 256, 0, stream>>>(Ae, Wt, fp(i_tb), (float*)d_out);

    dec_kernel<<<2048, 256, 0, stream>>>(
        (const float*)d_out, fp(7), fp(8), fp(9), fp(10),
        (const int*)d_in[11], fp(12),
        fp(i_d1 + 1), fp(i_d1 + 3), fp(i_d2 + 1), fp(i_d2 + 3),
        fp(i_d3), fp(i_d3 + 1), fp(i_d3 + 2), fp(i_d3 + 3),
        Pack, (float*)d_out);
}

// Round 15
// 342.545 us; speedup vs baseline: 1.1232x; 1.0098x over previous
//
#include <hip/hip_runtime.h>
#include <hip/hip_bf16.h>
#include <stdint.h>

// ---------------------------------------------------------------------------
// HandNet R17: R16 + enc full weight pre-stage.
// E1+E2+E3 are contiguous in Pack ([0,19200) fp16), so all three are staged
// once at kernel start (2400 uint4, hidden under the x/ea staging) -- the
// pattern validated for dec in R13. Removes the mid-kernel E3 restage
// (26.6KB global load stall) + one barrier. LDS 55.7->67.4KB keeps
// 2 blocks/CU (160/67.4 = 2.37, same floor as before): occupancy-free.
// enc3 reads WQ+5888. trans/dec/prep identical to R16 (345.9us validated;
// trans 72-73, FETCH 38MB).
// ---------------------------------------------------------------------------

#define ZSIZE 18874368   // 16384*1152  (z output)
#define AHALF 147456     // 8192*18     (ang half)
#define PHALF 442368     // AHALF*3     (pos half)

// ws layout (bytes)
#define WS_AE 0                  // 16384x1088 fp16 = 35651584
#define WS_WT 35651584           // 1152x1088 fp16  = 2506752
#define WS_PACK 38158336         // packed layer weights, 33280 fp16

// pack offsets (fp16 units) and padded row strides
#define P_E1 0        // enc1: 32 x 40
#define P_E2 1280     // enc2: 64 x 72
#define P_E3 5888     // enc3: 128 x 104  (E1..E3 contiguous: [0,19200))
#define P_D1 19200    // dec1: 64 x 168
#define P_D2 29952    // dec2: 32 x 104  (contiguous after D1)

using f32x4 = __attribute__((ext_vector_type(4))) float;
using f16x8 = __attribute__((ext_vector_type(8))) _Float16;
using f16x4 = __attribute__((ext_vector_type(4))) _Float16;

__device__ __forceinline__ float tanh_fast(float x) {
    x = fminf(40.f, fmaxf(-40.f, x));
    float e = __expf(2.f * x);
    return (e - 1.f) * __builtin_amdgcn_rcpf(e + 1.f);
}
__device__ __forceinline__ float lrelu(float x) { return x > 0.f ? x : 0.01f * x; }

__device__ __forceinline__ void gload_lds16(const void* g, void* l) {
    __builtin_amdgcn_global_load_lds(
        (__attribute__((address_space(1))) unsigned int*)g,
        (__attribute__((address_space(3))) unsigned int*)l, 16, 0, 0);
}

// ---------------------------------------------------------------------------
// prep_all: merged pack_weights (blocks 0..259) + Wt transpose (260..1483).
// ---------------------------------------------------------------------------
__global__ __launch_bounds__(256) void prep_all(
    _Float16* __restrict__ P,
    const float* __restrict__ W, _Float16* __restrict__ Wt,
    const float* __restrict__ e1l, const float* __restrict__ e1u,
    const float* __restrict__ e2l, const float* __restrict__ e2u,
    const float* __restrict__ e3l, const float* __restrict__ e3u,
    const float* __restrict__ d1l, const float* __restrict__ d1u,
    const float* __restrict__ d2l, const float* __restrict__ d2u)
{
    __shared__ float t[32][33];
    const int b = blockIdx.x;
    const int tid = threadIdx.x;

    if (b < 260) {
        const int p = b / 52;
        const int e = (b - p * 52) * 256 + tid;
        int Np, Kp, KpP, N, din, ed, K0, off; const float *Wl, *Wu;
        switch (p) {
          case 0:  Np=32;  Kp=32;  KpP=40;  N=16; din=3;  ed=3; K0=8;  off=P_E1; Wl=e1l; Wu=e1u; break;
          case 1:  Np=64;  Kp=64;  KpP=72;  N=32; din=16; ed=3; K0=24; off=P_E2; Wl=e2l; Wu=e2u; break;
          case 2:  Np=128; Kp=96;  KpP=104; N=64; din=32; ed=3; K0=40; off=P_E3; Wl=e3l; Wu=e3u; break;
          case 3:  Np=64;  Kp=160; KpP=168; N=32; din=66; ed=6; K0=72; off=P_D1; Wl=d1l; Wu=d1u; break;
          default: Np=32;  Kp=96;  KpP=104; N=16; din=32; ed=6; K0=40; off=P_D2; Wl=d2l; Wu=d2u; break;
        }
        if (e >= Np * KpP) return;
        const int n = e / KpP, k = e - n * KpP;
        float v = 0.f;
        if (k < Kp) {
            if (n < N) {
                if (k < din)                          v = Wl[k * N + n];
                else if (k >= K0 && k < K0 + din)     v = Wl[(din + k - K0) * N + n];
                else if (k >= 2*K0 && k < 2*K0 + ed)  v = Wl[(2*din + k - 2*K0) * N + n];
            } else {
                if (k < din) v = Wu[k * N + (n - N)];
            }
        }
        P[off + e] = (_Float16)v;
    } else {
        const int pb = b - 260;
        const int bx = pb % 34, by = pb / 34;
        const int k0 = bx * 32, n0 = by * 32;
        const int tx = tid & 31, ty = tid >> 5;
        for (int i = ty; i < 32; i += 8)
            t[i][tx] = W[(size_t)(k0 + i) * 1152 + n0 + tx];
        __syncthreads();
        for (int i = ty; i < 32; i += 8)
            Wt[(size_t)(n0 + i) * 1088 + k0 + tx] = (_Float16)t[tx][i];
    }
}

// ---------------------------------------------------------------------------
// Fused encoder on MFMA: 8 graphs/block, nodes padded to 20 -> M=160 (10 Mt).
// Activation strides (fp16): x 8, ea 16, h1 24, h2 40 (all zero-padded).
// LDS map (fp16 units): SX 0(1280) | EA 1280(2560) | H1 3840(3840) |
//                       H2 7680(6400) | WQ 14080(19200: E1+E2+E3) -> 33280.
// ALL weights staged once at start (contiguous in pack); enc2 reads WQ+1280,
// enc3 reads WQ+5888. No mid-kernel restage.
// M-tiles per wave: {wave, wave+4, wave+8<10} (dec-proven pattern).
// ---------------------------------------------------------------------------
#define E_SX 0
#define E_EA 1280
#define E_H1 3840
#define E_H2 7680
#define E_WQ 14080

__global__ __launch_bounds__(256) void enc_kernel(
    const float* __restrict__ lx,  const float* __restrict__ rx,
    const float* __restrict__ lea, const float* __restrict__ rea,
    const float* __restrict__ b1l, const float* __restrict__ b1u,
    const float* __restrict__ b2l, const float* __restrict__ b2u,
    const float* __restrict__ b3l, const float* __restrict__ b3u,
    const _Float16* __restrict__ pack,
    _Float16* __restrict__ Ae)
{
    __shared__ __align__(16) _Float16 sm[33280];
    __shared__ float sb[224];

    const int tid = threadIdx.x;
    const int wave = tid >> 6, lane = tid & 63;
    const int quad = lane >> 4, l16 = lane & 15;
    const int g2b = blockIdx.x * 8;

    // zero activation pool (14080 fp16 = 7040 u32)
    for (int i = tid; i < 7040; i += 256) ((uint32_t*)sm)[i] = 0u;
    // E1+E2+E3 weights (19200 fp16 = 2400 uint4, contiguous in pack)
    { uint4* d = (uint4*)&sm[E_WQ]; const uint4* s = (const uint4*)(pack + P_E1);
      for (int i = tid; i < 2400; i += 256) d[i] = s[i]; }
    for (int i = tid; i < 16; i += 256) { sb[i] = b1l[i]; sb[16 + i] = b1u[i]; }
    for (int i = tid; i < 32; i += 256) { sb[32 + i] = b2l[i]; sb[64 + i] = b2u[i]; }
    for (int i = tid; i < 64; i += 256) { sb[96 + i] = b3l[i]; sb[160 + i] = b3u[i]; }
    __syncthreads();

    // stage x, ea (8 graphs, all on same hand since g2b % 8 == 0)
    const float* xs = (g2b < 8192) ? lx  + (size_t)g2b * 51 : rx  + (size_t)(g2b - 8192) * 51;
    const float* es = (g2b < 8192) ? lea + (size_t)g2b * 48 : rea + (size_t)(g2b - 8192) * 48;
    for (int i = tid; i < 408; i += 256) {
        int g = i / 51, j = i - g * 51, node = j / 3, c = j - node * 3;
        sm[E_SX + (g * 20 + node) * 8 + c] = (_Float16)xs[i];
    }
    for (int i = tid; i < 384; i += 256) {
        int g = i / 48, j = i - g * 48, node = j / 3, c = j - node * 3;
        sm[E_EA + (g * 20 + node) * 16 + c] = (_Float16)es[i];
    }
    __syncthreads();

    // M-tiles owned: {wave, wave+4, wave+8<10}
    int mts[3] = { wave, wave + 4, wave + 8 };
    const bool has[3] = { true, true, wave < 2 };
    int gN[3], ndN[3], npN[3];
    #pragma unroll
    for (int t = 0; t < 3; t++) {
        const int r16 = mts[t] * 16 + l16;
        gN[t] = r16 / 20; ndN[t] = r16 - gN[t] * 20;
        npN[t] = ndN[t] ? ndN[t] - 1 : 0;
    }

    // ---- enc1: K'=32 (1 Kt), N'=32 (2 Nt) ----
    {
        f32x4 acc[3][2];
        #pragma unroll
        for (int t = 0; t < 3; t++)
            #pragma unroll
            for (int n = 0; n < 2; n++)
                #pragma unroll
                for (int r = 0; r < 4; r++) acc[t][n][r] = 0.f;
        f16x8 bfr[2];
        #pragma unroll
        for (int nt = 0; nt < 2; nt++)
            bfr[nt] = *(const f16x8*)&sm[E_WQ + (nt * 16 + l16) * 40 + quad * 8];
        #pragma unroll
        for (int t = 0; t < 3; t++) if (has[t]) {
            const int aD = E_SX + (gN[t] * 20 + ndN[t]) * 8;
            const int aS = E_SX + (gN[t] * 20 + npN[t]) * 8;
            const int aE = E_EA + (gN[t] * 20 + npN[t]) * 16;
            const int ch = quad;
            const int off = ch < 1 ? aD : (ch < 2 ? aS : aE + (ch - 2) * 8);
            f16x8 af = *(const f16x8*)&sm[off];
            #pragma unroll
            for (int nt = 0; nt < 2; nt++)
                acc[t][nt] = __builtin_amdgcn_mfma_f32_16x16x32_f16(af, bfr[nt], acc[t][nt], 0, 0, 0);
        }
        const int f = l16;
        #pragma unroll
        for (int t = 0; t < 3; t++) if (has[t]) {
            #pragma unroll
            for (int r = 0; r < 4; r++) {
                const int row = mts[t] * 16 + quad * 4 + r;
                const int g = row / 20, nd = row - g * 20;
                if (nd < 17) {
                    const float msg = acc[t][0][r] + sb[f];
                    const float u   = acc[t][1][r] + sb[16 + f];
                    sm[E_H1 + (g * 20 + nd) * 24 + f] =
                        (_Float16)(u + (nd ? lrelu(msg) : 0.f));
                }
            }
        }
    }
    __syncthreads();

    // ---- enc2: K'=64 (2 Kt), N'=64 (4 Nt), weights at WQ+1280 ----
    {
        f32x4 acc[3][4];
        #pragma unroll
        for (int t = 0; t < 3; t++)
            #pragma unroll
            for (int n = 0; n < 4; n++)
                #pragma unroll
                for (int r = 0; r < 4; r++) acc[t][n][r] = 0.f;
        #pragma unroll
        for (int Kt = 0; Kt < 2; Kt++) {
            f16x8 bfr[4];
            #pragma unroll
            for (int nt = 0; nt < 4; nt++)
                bfr[nt] = *(const f16x8*)&sm[E_WQ + 1280 + (nt * 16 + l16) * 72 + Kt * 32 + quad * 8];
            #pragma unroll
            for (int t = 0; t < 3; t++) if (has[t]) {
                const int aD = E_H1 + (gN[t] * 20 + ndN[t]) * 24;
                const int aS = E_H1 + (gN[t] * 20 + npN[t]) * 24;
                const int aE = E_EA + (gN[t] * 20 + npN[t]) * 16;
                const int ch = Kt * 4 + quad;
                const int off = ch < 3 ? aD + ch * 8
                              : (ch < 6 ? aS + (ch - 3) * 8 : aE + (ch - 6) * 8);
                f16x8 af = *(const f16x8*)&sm[off];
                #pragma unroll
                for (int nt = 0; nt < 4; nt++)
                    acc[t][nt] = __builtin_amdgcn_mfma_f32_16x16x32_f16(af, bfr[nt], acc[t][nt], 0, 0, 0);
            }
        }
        #pragma unroll
        for (int ntm = 0; ntm < 2; ntm++) {
            const int f = ntm * 16 + l16;
            #pragma unroll
            for (int t = 0; t < 3; t++) if (has[t]) {
                #pragma unroll
                for (int r = 0; r < 4; r++) {
                    const int row = mts[t] * 16 + quad * 4 + r;
                    const int g = row / 20, nd = row - g * 20;
                    if (nd < 17) {
                        const float msg = acc[t][ntm][r]     + sb[32 + f];
                        const float u   = acc[t][ntm + 2][r] + sb[64 + f];
                        sm[E_H2 + (g * 20 + nd) * 40 + f] =
                            (_Float16)(u + (nd ? lrelu(msg) : 0.f));
                    }
                }
            }
        }
    }
    __syncthreads();

    // ---- enc3: K'=96 (3 Kt), N'=128 (8 Nt), weights at WQ+5888 -> Ae ----
    {
        f32x4 acc[3][8];
        #pragma unroll
        for (int t = 0; t < 3; t++)
            #pragma unroll
            for (int n = 0; n < 8; n++)
                #pragma unroll
                for (int r = 0; r < 4; r++) acc[t][n][r] = 0.f;
        #pragma unroll
        for (int Kt = 0; Kt < 3; Kt++) {
            f16x8 bfr[8];
            #pragma unroll
            for (int nt = 0; nt < 8; nt++)
                bfr[nt] = *(const f16x8*)&sm[E_WQ + 5888 + (nt * 16 + l16) * 104 + Kt * 32 + quad * 8];
            #pragma unroll
            for (int t = 0; t < 3; t++) if (has[t]) {
                const int aD = E_H2 + (gN[t] * 20 + ndN[t]) * 40;
                const int aS = E_H2 + (gN[t] * 20 + npN[t]) * 40;
                const int aE = E_EA + (gN[t] * 20 + npN[t]) * 16;
                const int ch = Kt * 4 + quad;
                const int off = ch < 5 ? aD + ch * 8
                              : (ch < 10 ? aS + (ch - 5) * 8 : aE + (ch - 10) * 8);
                f16x8 af = *(const f16x8*)&sm[off];
                #pragma unroll
                for (int nt = 0; nt < 8; nt++)
                    acc[t][nt] = __builtin_amdgcn_mfma_f32_16x16x32_f16(af, bfr[nt], acc[t][nt], 0, 0, 0);
            }
        }
        #pragma unroll
        for (int ntm = 0; ntm < 4; ntm++) {
            const int f = ntm * 16 + l16;
            #pragma unroll
            for (int t = 0; t < 3; t++) if (has[t]) {
                #pragma unroll
                for (int r = 0; r < 4; r++) {
                    const int row = mts[t] * 16 + quad * 4 + r;
                    const int g = row / 20, nd = row - g * 20;
                    if (nd < 17) {
                        const float msg = acc[t][ntm][r]     + sb[96 + f];
                        const float u   = acc[t][ntm + 4][r] + sb[160 + f];
                        Ae[(size_t)(g2b + g) * 1088 + nd * 64 + f] =
                            (_Float16)(u + (nd ? lrelu(msg) : 0.f));
                    }
                }
            }
        }
    }
}

// ---------------------------------------------------------------------------
// trans GEMM fp16: 128x128 C-tile, K-step 32, 3-buffer LDS ring, 2 stages in
// flight across a raw s_barrier guarded by counted s_waitcnt vmcnt(4) (R8
// structure, best measured). 1D grid + bijective XCD-chunk swizzle (R11).
// Fast-tanh epilogue (R12).
// ---------------------------------------------------------------------------
__global__ __launch_bounds__(256) void trans_gemm(
    const _Float16* __restrict__ A, const _Float16* __restrict__ Bt,
    const float* __restrict__ bias, float* __restrict__ Z)
{
    __shared__ __align__(16) _Float16 As[3][128 * 32];
    __shared__ __align__(16) _Float16 Bs[3][128 * 32];
    const int tid = threadIdx.x;

    // XCD-chunk swizzle: 1152 blocks, 8 XCDs, 144 blocks/XCD chunk.
    const int id = blockIdx.x;
    const int swz = (id & 7) * 144 + (id >> 3);
    const int bm = (swz / 9) * 128, bn = (swz % 9) * 128;

    const int lane = tid & 63, wave = tid >> 6;
    const int wr = wave >> 1, wc = wave & 1;
    const int quad = lane >> 4, l16 = lane & 15;

    const int row0 = wave * 32 + (lane >> 2);
    const int row1 = row0 + 16;
    const int q0 = (lane & 3) ^ ((row0 >> 1) & 3);
    const int q1 = (lane & 3) ^ ((row1 >> 1) & 3);
    const size_t gA0 = (size_t)(bm + row0) * 1088 + q0 * 8;
    const size_t gA1 = (size_t)(bm + row1) * 1088 + q1 * 8;
    const size_t gB0 = (size_t)(bn + row0) * 1088 + q0 * 8;
    const size_t gB1 = (size_t)(bn + row1) * 1088 + q1 * 8;
    const int ldsA0 = (wave * 32) * 32;
    const int ldsA1 = (wave * 32 + 16) * 32;

    int offA[4], offB[4];
    #pragma unroll
    for (int i = 0; i < 4; i++) {
        const int ma = wr * 64 + i * 16 + l16;
        offA[i] = ma * 32 + (quad ^ ((ma >> 1) & 3)) * 8;
        const int nb = wc * 64 + i * 16 + l16;
        offB[i] = nb * 32 + (quad ^ ((nb >> 1) & 3)) * 8;
    }

    f32x4 acc[4][4];
    #pragma unroll
    for (int i = 0; i < 4; i++)
        #pragma unroll
        for (int j = 0; j < 4; j++)
            #pragma unroll
            for (int r = 0; r < 4; r++) acc[i][j][r] = 0.f;

    // prologue: stage tiles 0 and 1 into buffers 0 and 1 (8 loads in flight)
    gload_lds16(A + gA0,       &As[0][ldsA0]);
    gload_lds16(A + gA1,       &As[0][ldsA1]);
    gload_lds16(Bt + gB0,      &Bs[0][ldsA0]);
    gload_lds16(Bt + gB1,      &Bs[0][ldsA1]);
    gload_lds16(A + gA0 + 32,  &As[1][ldsA0]);
    gload_lds16(A + gA1 + 32,  &As[1][ldsA1]);
    gload_lds16(Bt + gB0 + 32, &Bs[1][ldsA0]);
    gload_lds16(Bt + gB1 + 32, &Bs[1][ldsA1]);

    int cb = 0;   // consume buffer index (t % 3)
    int sb = 2;   // stage buffer index ((t+2) % 3)
    for (int t = 0; t < 34; ++t) {
        // wait for own stage-t loads (oldest 4), keep t+1/t+2 in flight
        if (t < 33) asm volatile("s_waitcnt vmcnt(4)" ::: "memory");
        else        asm volatile("s_waitcnt vmcnt(0)" ::: "memory");
        __builtin_amdgcn_s_barrier();
        if (t + 2 < 34) {
            const int k0 = (t + 2) * 32;
            gload_lds16(A + gA0 + k0,  &As[sb][ldsA0]);
            gload_lds16(A + gA1 + k0,  &As[sb][ldsA1]);
            gload_lds16(Bt + gB0 + k0, &Bs[sb][ldsA0]);
            gload_lds16(Bt + gB1 + k0, &Bs[sb][ldsA1]);
        }
        f16x8 af[4], bfr[4];
        #pragma unroll
        for (int mi = 0; mi < 4; mi++) af[mi]  = *(const f16x8*)&As[cb][offA[mi]];
        #pragma unroll
        for (int ni = 0; ni < 4; ni++) bfr[ni] = *(const f16x8*)&Bs[cb][offB[ni]];
        #pragma unroll
        for (int mi = 0; mi < 4; mi++)
            #pragma unroll
            for (int ni = 0; ni < 4; ni++)
                acc[mi][ni] = __builtin_amdgcn_mfma_f32_16x16x32_f16(
                    af[mi], bfr[ni], acc[mi][ni], 0, 0, 0);
        cb = (cb == 2) ? 0 : cb + 1;
        sb = (sb == 2) ? 0 : sb + 1;
    }

    #pragma unroll
    for (int mi = 0; mi < 4; mi++) {
        #pragma unroll
        for (int ni = 0; ni < 4; ni++) {
            const int n = bn + wc * 64 + ni * 16 + l16;
            const float bv = bias[n];
            #pragma unroll
            for (int r = 0; r < 4; r++) {
                const int m = bm + wr * 64 + mi * 16 + quad * 4 + r;
                Z[(size_t)m * 1152 + n] = tanh_fast(acc[mi][ni][r] + bv);
            }
        }
    }
}

// ---------------------------------------------------------------------------
// Fused decoder + FK on MFMA: 8 graphs/block, M=160 (10 Mt).
// Strides (fp16): xd 72, ea 16, h1 40, h2 16.
// LDS map (fp16): XD 0(11520) | EA 11520(2560) | H1 14080(6400) |
//                 H2 20480(2560) | WQ 23040(14080: D1+D2) -> pool 37120.
// D1+D2 staged once at start (contiguous in Pack); dec2 reads WQ+10752.
// FK/angle data staged in f32 LDS: ax 432, off 432, lo 144, up 144.
// ---------------------------------------------------------------------------
#define D_XD 0
#define D_EA 11520
#define D_H1 14080
#define D_H2 20480
#define D_WQ 23040
#define SB_B1L 0
#define SB_B1U 32
#define SB_B2L 64
#define SB_B2U 80
#define SB_W3L 96
#define SB_W3U 134
#define SB_B3L 150
#define SB_B3U 151
#define SB_ANG 152   // 144 floats

__global__ __launch_bounds__(256) void dec_kernel(
    const float* __restrict__ Zc,  const float* __restrict__ tea,
    const float* __restrict__ lo_, const float* __restrict__ up_,
    const float* __restrict__ off_, const int* __restrict__ par_,
    const float* __restrict__ ax_,
    const float* __restrict__ b1l, const float* __restrict__ b1u,
    const float* __restrict__ b2l, const float* __restrict__ b2u,
    const float* __restrict__ w3l, const float* __restrict__ b3l,
    const float* __restrict__ w3u, const float* __restrict__ b3u,
    const _Float16* __restrict__ pack,
    float* __restrict__ out)
{
    __shared__ __align__(16) _Float16 sm[37120];
    __shared__ __align__(16) float sfl[296];
    __shared__ __align__(16) float s_ax[432];
    __shared__ __align__(16) float s_off[432];
    __shared__ __align__(16) float s_lo[144];
    __shared__ __align__(16) float s_up[144];

    const int tid = threadIdx.x;
    const int wave = tid >> 6, lane = tid & 63;
    const int quad = lane >> 4, l16 = lane & 15;
    const int g2b = blockIdx.x * 8;
    const int hb = g2b & 8191;     // 8 graphs per block, same hand (g2b % 8 == 0)

    // zero activations (23040 fp16 = 11520 u32)
    for (int i = tid; i < 11520; i += 256) ((uint32_t*)sm)[i] = 0u;
    // D1+D2 weights (14080 fp16 = 1760 uint4, contiguous in pack)
    { uint4* d = (uint4*)&sm[D_WQ]; const uint4* s = (const uint4*)(pack + P_D1);
      for (int i = tid; i < 1760; i += 256) d[i] = s[i]; }
    for (int i = tid; i < 32; i += 256) { sfl[SB_B1L + i] = b1l[i]; sfl[SB_B1U + i] = b1u[i]; }
    for (int i = tid; i < 16; i += 256) { sfl[SB_B2L + i] = b2l[i]; sfl[SB_B2U + i] = b2u[i];
                                          sfl[SB_W3U + i] = w3u[i]; }
    for (int i = tid; i < 38; i += 256) sfl[SB_W3L + i] = w3l[i];
    if (tid == 0) { sfl[SB_B3L] = b3l[0]; sfl[SB_B3U] = b3u[0]; }

    // FK / angle inputs, coalesced float4 (all bases 16B-aligned: hb % 8 == 0)
    {
        const f32x4* axv = (const f32x4*)(ax_  + (size_t)hb * 54);
        const f32x4* ofv = (const f32x4*)(off_ + (size_t)hb * 54);
        for (int i = tid; i < 108; i += 256) {
            ((f32x4*)s_ax)[i]  = axv[i];
            ((f32x4*)s_off)[i] = ofv[i];
        }
        const f32x4* lov = (const f32x4*)(lo_ + (size_t)hb * 18);
        const f32x4* upv = (const f32x4*)(up_ + (size_t)hb * 18);
        for (int i = tid; i < 36; i += 256) {
            ((f32x4*)s_lo)[i] = lov[i];
            ((f32x4*)s_up)[i] = upv[i];
        }
    }
    __syncthreads();

    // stage xd = [z(64) | lo | up], ea -- vectorized
    {
        // z: 9216 f32 contiguous = 2304 float4, 9 per thread
        const f32x4* Zv = (const f32x4*)(Zc + (size_t)g2b * 1152);
        for (int i = tid; i < 2304; i += 256) {
            const f32x4 v = Zv[i];
            const int g = i / 288, rem = i - g * 288;
            const int node = rem >> 4, c = (rem & 15) << 2;
            f16x4 h;
            h[0] = (_Float16)v[0]; h[1] = (_Float16)v[1];
            h[2] = (_Float16)v[2]; h[3] = (_Float16)v[3];
            *(f16x4*)&sm[D_XD + (g * 20 + node) * 72 + c] = h;
        }
        // lo/up into xd cols 64,65 (from LDS f32 copies)
        for (int i = tid; i < 144; i += 256) {
            const int g = i / 18, node = i - g * 18;
            sm[D_XD + (g * 20 + node) * 72 + 64] = (_Float16)s_lo[i];
            sm[D_XD + (g * 20 + node) * 72 + 65] = (_Float16)s_up[i];
        }
        // ea: 816 f32 contiguous = 204 float4 (graph stride 102 not /4 -> per-elem scatter)
        const f32x4* Ev = (const f32x4*)(tea + (size_t)hb * 102);
        for (int i = tid; i < 204; i += 256) {
            const f32x4 v = Ev[i];
            #pragma unroll
            for (int e = 0; e < 4; e++) {
                const int f = 4 * i + e;
                const int g = f / 102, j = f - 102 * g;
                const int node = j / 6, c = j - node * 6;
                sm[D_EA + (g * 20 + node) * 16 + c] = (_Float16)v[e];
            }
        }
    }
    __syncthreads();

    // M-tiles owned: {wave, wave+4, wave+8<10}
    int mts[3] = { wave, wave + 4, wave + 8 };
    const bool has[3] = { true, true, wave < 2 };
    int gN[3], ndN[3], npN[3];
    #pragma unroll
    for (int t = 0; t < 3; t++) {
        const int r16 = mts[t] * 16 + l16;
        gN[t] = r16 / 20; ndN[t] = r16 - gN[t] * 20;
        npN[t] = ndN[t] ? ndN[t] - 1 : 0;
    }

    // ---- dec1: K'=160 (5 Kt), N'=64 (4 Nt) ----
    {
        f32x4 acc[3][4];
        #pragma unroll
        for (int t = 0; t < 3; t++)
            #pragma unroll
            for (int n = 0; n < 4; n++)
                #pragma unroll
                for (int r = 0; r < 4; r++) acc[t][n][r] = 0.f;
        #pragma unroll
        for (int Kt = 0; Kt < 5; Kt++) {
            f16x8 bfr[4];
            #pragma unroll
            for (int nt = 0; nt < 4; nt++)
                bfr[nt] = *(const f16x8*)&sm[D_WQ + (nt * 16 + l16) * 168 + Kt * 32 + quad * 8];
            #pragma unroll
            for (int t = 0; t < 3; t++) if (has[t]) {
                const int aD = D_XD + (gN[t] * 20 + ndN[t]) * 72;
                const int aS = D_XD + (gN[t] * 20 + npN[t]) * 72;
                const int aE = D_EA + (gN[t] * 20 + npN[t]) * 16;
                const int ch = Kt * 4 + quad;
                const int off = ch < 9 ? aD + ch * 8
                              : (ch < 18 ? aS + (ch - 9) * 8 : aE + (ch - 18) * 8);
                f16x8 af = *(const f16x8*)&sm[off];
                #pragma unroll
                for (int nt = 0; nt < 4; nt++)
                    acc[t][nt] = __builtin_amdgcn_mfma_f32_16x16x32_f16(af, bfr[nt], acc[t][nt], 0, 0, 0);
            }
        }
        #pragma unroll
        for (int ntm = 0; ntm < 2; ntm++) {
            const int f = ntm * 16 + l16;
            #pragma unroll
            for (int t = 0; t < 3; t++) if (has[t]) {
                #pragma unroll
                for (int r = 0; r < 4; r++) {
                    const int row = mts[t] * 16 + quad * 4 + r;
                    const int g = row / 20, nd = row - g * 20;
                    if (nd < 18) {
                        const float msg = acc[t][ntm][r]     + sfl[SB_B1L + f];
                        const float u   = acc[t][ntm + 2][r] + sfl[SB_B1U + f];
                        sm[D_H1 + (g * 20 + nd) * 40 + f] =
                            (_Float16)(u + (nd ? lrelu(msg) : 0.f));
                    }
                }
            }
        }
    }
    __syncthreads();

    // ---- dec2: K'=96 (3 Kt), N'=32 (2 Nt), weights at WQ+10752 ----
    {
        f32x4 acc[3][2];
        #pragma unroll
        for (int t = 0; t < 3; t++)
            #pragma unroll
            for (int n = 0; n < 2; n++)
                #pragma unroll
                for (int r = 0; r < 4; r++) acc[t][n][r] = 0.f;
        #pragma unroll
        for (int Kt = 0; Kt < 3; Kt++) {
            f16x8 bfr[2];
            #pragma unroll
            for (int nt = 0; nt < 2; nt++)
                bfr[nt] = *(const f16x8*)&sm[D_WQ + 10752 + (nt * 16 + l16) * 104 + Kt * 32 + quad * 8];
            #pragma unroll
            for (int t = 0; t < 3; t++) if (has[t]) {
                const int aD = D_H1 + (gN[t] * 20 + ndN[t]) * 40;
                const int aS = D_H1 + (gN[t] * 20 + npN[t]) * 40;
                const int aE = D_EA + (gN[t] * 20 + npN[t]) * 16;
                const int ch = Kt * 4 + quad;
                const int off = ch < 5 ? aD + ch * 8
                              : (ch < 10 ? aS + (ch - 5) * 8 : aE + (ch - 10) * 8);
                f16x8 af = *(const f16x8*)&sm[off];
                #pragma unroll
                for (int nt = 0; nt < 2; nt++)
                    acc[t][nt] = __builtin_amdgcn_mfma_f32_16x16x32_f16(af, bfr[nt], acc[t][nt], 0, 0, 0);
            }
        }
        const int f = l16;
        #pragma unroll
        for (int t = 0; t < 3; t++) if (has[t]) {
            #pragma unroll
            for (int r = 0; r < 4; r++) {
                const int row = mts[t] * 16 + quad * 4 + r;
                const int g = row / 20, nd = row - g * 20;
                if (nd < 18) {
                    const float msg = acc[t][0][r] + sfl[SB_B2L + f];
                    const float u   = acc[t][1][r] + sfl[SB_B2U + f];
                    sm[D_H2 + (g * 20 + nd) * 16 + f] =
                        (_Float16)(u + (nd ? lrelu(msg) : 0.f));
                }
            }
        }
    }
    __syncthreads();

    // ---- dec3 (N=1) + tanh + angle (VALU) ----
    if (tid < 144) {
        const int g = tid / 18, nd = tid - (tid / 18) * 18;
        const _Float16* hn = &sm[D_H2 + (g * 20 + nd) * 16];
        float acc = sfl[SB_B3U];
        #pragma unroll
        for (int c = 0; c < 16; c++) acc += (float)hn[c] * sfl[SB_W3U + c];
        if (nd > 0) {
            const _Float16* hp = &sm[D_H2 + (g * 20 + nd - 1) * 16];
            const _Float16* e  = &sm[D_EA + (g * 20 + nd - 1) * 16];
            float m = sfl[SB_B3L];
            #pragma unroll
            for (int c = 0; c < 16; c++) m += (float)hn[c] * sfl[SB_W3L + c];
            #pragma unroll
            for (int c = 0; c < 16; c++) m += (float)hp[c] * sfl[SB_W3L + 16 + c];
            #pragma unroll
            for (int c = 0; c < 6;  c++) m += (float)e[c]  * sfl[SB_W3L + 32 + c];
            acc += lrelu(m);
        }
        const float hd = tanh_fast(acc);
        const int g2 = g2b + g;
        const float lo = s_lo[tid], up = s_up[tid];
        const float ang = lo + (up - lo) * (hd + 1.f) * 0.5f;
        sfl[SB_ANG + tid] = ang;
        const size_t abase = (g2 < 8192) ? (size_t)ZSIZE + (size_t)g2 * 18
                                         : (size_t)ZSIZE + AHALF + PHALF + (size_t)(g2 - 8192) * 18;
        out[abase + nd] = ang;
    }
    __syncthreads();

    // ---- FK: sequential 18-joint chain, 3 threads per graph (one per row of
    // R). Row r of R_new = row r of R_prev times full local Rl; p_r needs only
    // row r of R_prev. All inputs from LDS (staged at kernel start); chain
    // topology (root j=0, parent j-1) as assumed by the message passing.
    if (tid < 24) {
        const int g = tid / 3, r = tid - (tid / 3) * 3;
        const int g2 = g2b + g;
        const size_t pbase = (g2 < 8192)
            ? (size_t)ZSIZE + AHALF + (size_t)g2 * 54
            : (size_t)ZSIZE + AHALF + PHALF + AHALF + (size_t)(g2 - 8192) * 54;
        float Rr0 = 0.f, Rr1 = 0.f, Rr2 = 0.f, pr = 0.f;
        #pragma unroll
        for (int j = 0; j < 18; j++) {
            const int m = g * 18 + j;
            const float a0 = s_ax[m * 3 + 0], a1 = s_ax[m * 3 + 1], a2 = s_ax[m * 3 + 2];
            const float o0 = s_off[m * 3 + 0], o1 = s_off[m * 3 + 1], o2 = s_off[m * 3 + 2];
            float s, c;
            __sincosf(sfl[SB_ANG + m], &s, &c);
            const float omc = 1.f - c;
            const float n2 = a0 * a0 + a1 * a1 + a2 * a2;
            const float dg = 1.f - omc * n2;
            const float L00 = dg + omc * a0 * a0;
            const float L01 = omc * a0 * a1 - s * a2;
            const float L02 = omc * a0 * a2 + s * a1;
            const float L10 = omc * a1 * a0 + s * a2;
            const float L11 = dg + omc * a1 * a1;
            const float L12 = omc * a1 * a2 - s * a0;
            const float L20 = omc * a2 * a0 - s * a1;
            const float L21 = omc * a2 * a1 + s * a0;
            const float L22 = dg + omc * a2 * a2;
            if (j == 0) {
                Rr0 = (r == 0) ? L00 : ((r == 1) ? L10 : L20);
                Rr1 = (r == 0) ? L01 : ((r == 1) ? L11 : L21);
                Rr2 = (r == 0) ? L02 : ((r == 1) ? L12 : L22);
                pr  = (r == 0) ? o0  : ((r == 1) ? o1  : o2);
            } else {
                pr += Rr0 * o0 + Rr1 * o1 + Rr2 * o2;
                const float t0 = Rr0 * L00 + Rr1 * L10 + Rr2 * L20;
                const float t1 = Rr0 * L01 + Rr1 * L11 + Rr2 * L21;
                const float t2 = Rr0 * L02 + Rr1 * L12 + Rr2 * L22;
                Rr0 = t0; Rr1 = t1; Rr2 = t2;
            }
            out[pbase + j * 3 + r] = pr;
        }
    }
}

// ---------------------------------------------------------------------------
extern "C" void kernel_launch(void* const* d_in, const int* in_sizes, int n_in,
                              void* d_out, int out_size, void* d_ws, size_t ws_size,
                              hipStream_t stream)
{
    int i_tw, i_tb, i_d1, i_d2, i_d3;
    if (n_in > 27 && in_sizes[26] == 1088 * 1152) {
        i_tw = 26; i_tb = 27; i_d1 = 28; i_d2 = 32; i_d3 = 36;
    } else {
        i_d1 = 26; i_d2 = 30; i_d3 = 34; i_tw = 38; i_tb = 39;
    }
    auto fp = [&](int i) { return (const float*)d_in[i]; };

    _Float16* Ae   = (_Float16*)((char*)d_ws + WS_AE);
    _Float16* Wt   = (_Float16*)((char*)d_ws + WS_WT);
    _Float16* Pack = (_Float16*)((char*)d_ws + WS_PACK);

    prep_all<<<1484, 256, 0, stream>>>(
        Pack, fp(i_tw), Wt,
        fp(14), fp(16), fp(18), fp(20), fp(22), fp(24),
        fp(i_d1), fp(i_d1 + 2), fp(i_d2), fp(i_d2 + 2));

    enc_kernel<<<2048, 256, 0, stream>>>(
        fp(0), fp(1), fp(4), fp(5),
        fp(15), fp(17), fp(19), fp(21), fp(23), fp(25),
        Pack, Ae);

    trans_gemm<<<1152, 256, 0, stream>>>(Ae, Wt, fp(i_tb), (float*)d_out);

    dec_kernel<<<2048, 256, 0, stream>>>(
        (const float*)d_out, fp(7), fp(8), fp(9), fp(10),
        (const int*)d_in[11], fp(12),
        fp(i_d1 + 1), fp(i_d1 + 3), fp(i_d2 + 1), fp(i_d2 + 3),
        fp(i_d3), fp(i_d3 + 1), fp(i_d3 + 2), fp(i_d3 + 3),
        Pack, (float*)d_out);
}